// Round 2
// baseline (1162.635 us; speedup 1.0000x reference)
//
#include <hip/hip_runtime.h>
#include <cstdint>
#include <cstddef>

// ---------------------------------------------------------------------------
// Model_xLSTM: B=128 S=256 NF=32 E=4 D=256 H=4 DI=512 DHM=128 DHS=64 K=4 FF=352
// Round 7: scan -> remove per-step vmcnt drain at __syncthreads (the implicit
// s_waitcnt vmcnt(0) before s_barrier serialized ~500-900cy of gate/Xr load
// latency into EVERY step). Gate streams + Xr rows now chunk-preloaded into
// registers (16 steps/chunk, unrolled); wave4 batches 16 stores per chunk;
// wave4 headnorm reduction switched from shfl_xor (6 dep ds_swizzle) to DPP
// row_shr/row_bcast (+readlane 63). 5-wave structure/barriers unchanged (R6).
// Rest frozen (R4/R5).
// ---------------------------------------------------------------------------

using u16 = unsigned short;
using u32 = unsigned int;

typedef __attribute__((ext_vector_type(8))) short short8;
typedef __attribute__((ext_vector_type(8))) unsigned short ushort8v;
typedef __attribute__((ext_vector_type(4))) float float4v;

#define DEVINL __device__ __forceinline__

DEVINL float b2f(u16 u){ u32 x = ((u32)u) << 16; return __builtin_bit_cast(float, x); }
DEVINL u16 f2b(float f){
  u32 x = __builtin_bit_cast(u32, f);
  u32 r = x + 0x7FFFu + ((x >> 16) & 1u);   // RTNE
  return (u16)(r >> 16);
}
DEVINL float ldval(float x){ return x; }
DEVINL float ldval(u16 x){ return b2f(x); }
DEVINL void stval(float* p, float v){ *p = v; }
DEVINL void stval(u16* p, float v){ *p = f2b(v); }

// dual-chain 64-lane sum via DPP (gfx9 row ops), results broadcast via lane 63
DEVINL void dpp_sum2(float a, float b, float& oa, float& ob){
  int xa, xb;
  xa = __builtin_amdgcn_update_dpp(0, __builtin_bit_cast(int, a), 0x111, 0xf, 0xf, true);
  xb = __builtin_amdgcn_update_dpp(0, __builtin_bit_cast(int, b), 0x111, 0xf, 0xf, true);
  a += __builtin_bit_cast(float, xa); b += __builtin_bit_cast(float, xb);
  xa = __builtin_amdgcn_update_dpp(0, __builtin_bit_cast(int, a), 0x112, 0xf, 0xf, true);
  xb = __builtin_amdgcn_update_dpp(0, __builtin_bit_cast(int, b), 0x112, 0xf, 0xf, true);
  a += __builtin_bit_cast(float, xa); b += __builtin_bit_cast(float, xb);
  xa = __builtin_amdgcn_update_dpp(0, __builtin_bit_cast(int, a), 0x114, 0xf, 0xf, true);
  xb = __builtin_amdgcn_update_dpp(0, __builtin_bit_cast(int, b), 0x114, 0xf, 0xf, true);
  a += __builtin_bit_cast(float, xa); b += __builtin_bit_cast(float, xb);
  xa = __builtin_amdgcn_update_dpp(0, __builtin_bit_cast(int, a), 0x118, 0xf, 0xf, true);
  xb = __builtin_amdgcn_update_dpp(0, __builtin_bit_cast(int, b), 0x118, 0xf, 0xf, true);
  a += __builtin_bit_cast(float, xa); b += __builtin_bit_cast(float, xb);
  xa = __builtin_amdgcn_update_dpp(0, __builtin_bit_cast(int, a), 0x142, 0xf, 0xf, true);
  xb = __builtin_amdgcn_update_dpp(0, __builtin_bit_cast(int, b), 0x142, 0xf, 0xf, true);
  a += __builtin_bit_cast(float, xa); b += __builtin_bit_cast(float, xb);
  xa = __builtin_amdgcn_update_dpp(0, __builtin_bit_cast(int, a), 0x143, 0xf, 0xf, true);
  xb = __builtin_amdgcn_update_dpp(0, __builtin_bit_cast(int, b), 0x143, 0xf, 0xf, true);
  a += __builtin_bit_cast(float, xa); b += __builtin_bit_cast(float, xb);
  oa = __builtin_bit_cast(float, __builtin_amdgcn_readlane(__builtin_bit_cast(int, a), 63));
  ob = __builtin_bit_cast(float, __builtin_amdgcn_readlane(__builtin_bit_cast(int, b), 63));
}

// ----------------------------- input table ---------------------------------
constexpr int IN_N = 56;
constexpr long long IN_SIZES[IN_N] = {
  1048576, 128, 128, 404, 28, 10240, 256, 256, 256,
  262144, 1024, 2048, 512,
  262144, 512, 262144, 512, 262144, 512,
  6144, 4, 6144, 4,
  512, 512, 512, 131072, 256,
  256, 256, 1024, 256,
  65536, 256, 65536, 256, 65536, 256, 65536, 256,
  16384, 16384, 16384, 16384,
  256, 256,
  256, 256, 180224, 704, 90112, 256,
  16384, 64, 192, 3 };

constexpr bool is_wt_input(int i){
  return i==9 || i==13 || i==15 || i==17 || i==26 || i==32 || i==34 || i==36
      || i==38 || i==48 || i==50;
}

struct CvOff { long long off[IN_N+1]; };
constexpr CvOff make_off(){
  CvOff o{};
  long long a = 0;
  for (int i = 0; i < IN_N; i++){
    o.off[i] = a;
    long long s = IN_SIZES[i];
    if (i == 1 || i == 2 || is_wt_input(i)) s = 0;
    a += s;
  }
  o.off[IN_N] = a;
  return o;
}
constexpr CvOff CVOFF = make_off();
constexpr long long CV_TOTAL = CVOFF.off[IN_N];

// transposed-weight table
constexpr int WT_NW = 11;
constexpr int WTB_IN[WT_NW] = {9, 13, 15, 17, 26, 32, 34, 36, 38, 48, 50};
constexpr int WTB_K[WT_NW]  = {256,512,512,512,512,256,256,256,256,256,352};
constexpr int WTB_N[WT_NW]  = {1024,512,512,512,256,256,256,256,256,704,256};
constexpr long long WTO[WT_NW+1] = {0, 262144, 524288, 786432, 1048576, 1179648,
  1245184, 1310720, 1376256, 1441792, 1622016, 1712128};
constexpr long long WT_ELEMS = WTO[WT_NW];

// ----------------------------- ws layout (float units) ---------------------
constexpr long long alignup(long long x){ return ((x + 255) / 256) * 256; }
constexpr long long TOK = 32768;            // B*S
constexpr long long OFF_FLAG = alignup(CV_TOTAL);
constexpr long long OFF_IP  = OFF_FLAG + 64;
constexpr long long OFF_FP  = OFF_IP  + 131072;
constexpr long long OFF_F   = OFF_FP  + 131072;
constexpr long long OFF_G   = OFF_F   + 131072;
constexpr long long OFF_M   = OFF_G   + 131072;
constexpr long long OFF_X   = OFF_M   + 131072;           // T x 256 fp32
constexpr long long OFF_XN  = OFF_X   + TOK*256;          // T x 256 bf16
constexpr long long OFF_UP  = OFF_XN  + TOK*128;          // T x 1024 bf16 (xm|zg)
constexpr long long OFF_A   = OFF_UP  + TOK*512;          // T x 512 bf16 (a / AC / P)
constexpr long long OFF_Q   = OFF_A   + TOK*256;          // T x 512 bf16 (q / Y / ZT fp32)
constexpr long long OFF_K   = OFF_Q   + TOK*256;          // T x 512 bf16 (k / IT fp32)
constexpr long long OFF_V   = OFF_K   + TOK*256;          // T x 512 bf16 (CAT / v / FT fp32)
constexpr long long OFF_WT  = OFF_V   + TOK*256;          // transposed bf16 weights
constexpr long long WS_END  = OFF_WT  + WT_ELEMS/2 + 256; // ~250 MiB

// ----------------------------- kernels -------------------------------------

__global__ void detect_kernel(const void* mlng, int* flag){
  if (threadIdx.x == 0){
    u32 u = *(const u32*)mlng;
    *flag = (u == 0x3F803F80u) ? 1 : 0;
  }
}

struct InPtrs { const void* p[IN_N]; };

__global__ __launch_bounds__(256) void convert_kernel(InPtrs ptrs, float* __restrict__ cv,
                                                      const int* __restrict__ flag){
  long long gid = (long long)blockIdx.x * 256 + threadIdx.x;
  if (gid >= CV_TOTAL) return;
  int seg = 0;
#pragma unroll
  for (int i = 1; i < IN_N; i++) seg += (gid >= CVOFF.off[i]) ? 1 : 0;
  long long local = gid - CVOFF.off[seg];
  float v;
  if (*flag) v = b2f(((const u16*)ptrs.p[seg])[local]);
  else       v = ((const float*)ptrs.p[seg])[local];
  cv[gid] = v;
}

// W[K][N] (fp32 or bf16 input) -> WT[N][K] bf16; 32x32 LDS tiles.
__global__ __launch_bounds__(256) void wtrans_kernel(InPtrs ptrs, u16* __restrict__ WTb,
                                                     const int* __restrict__ flag){
  int wz = blockIdx.z;
  int K = WTB_K[wz], N = WTB_N[wz];
  int n0 = blockIdx.x * 32, k0 = blockIdx.y * 32;
  if (n0 >= N || k0 >= K) return;
  const void* W = ptrs.p[WTB_IN[wz]];
  u16* WT = WTb + WTO[wz];
  __shared__ u16 tile[32][34];
  int tx = threadIdx.x & 31, ty = threadIdx.x >> 5;
  bool bf = (*flag != 0);
#pragma unroll
  for (int i = 0; i < 4; i++){
    size_t src = (size_t)(k0 + ty + i*8)*N + n0 + tx;
    tile[ty + i*8][tx] = bf ? ((const u16*)W)[src] : f2b(((const float*)W)[src]);
  }
  __syncthreads();
#pragma unroll
  for (int i = 0; i < 4; i++)
    WT[(size_t)(n0 + ty + i*8)*K + k0 + tx] = tile[tx][ty + i*8];
}

__global__ __launch_bounds__(256) void cat_kernel(const float* __restrict__ xs,
    const int* __restrict__ xe, const int* __restrict__ xp,
    const float* __restrict__ ee, const float* __restrict__ ep,
    float* __restrict__ CAT){
  int gid = blockIdx.x * 256 + threadIdx.x;   // T*40
  int c = gid % 40; int t = gid / 40; int b = t >> 8;
  float v;
  if (c < 32)      v = xs[(size_t)t*32 + c];
  else if (c < 36) v = ee[xe[b]*4 + (c - 32)];
  else             v = ep[xp[b]*4 + (c - 36)];
  CAT[(size_t)t*40 + c] = v;
}

// SIMT GEMM kept for W_in (K=40, fp32 in/out)
template<typename TA, typename TC>
__global__ __launch_bounds__(256) void gemm_kernel(
    const TA* __restrict__ A, int lda,
    const float* __restrict__ Wm, const float* __restrict__ bias,
    TC* __restrict__ Cc, int ldc, const float* __restrict__ resid,
    int M, int N, int K)
{
  __shared__ float As[16][68];
  __shared__ float Bs[16][68];
  const int bm = blockIdx.y * 64, bn = blockIdx.x * 64;
  const int tid = threadIdx.x, tx = tid & 15, ty = tid >> 4;
  float acc[4][4] = {};
  for (int k0 = 0; k0 < K; k0 += 16){
#pragma unroll
    for (int i = 0; i < 4; i++){
      int idx = tid + i*256;
      int m = idx >> 4, kq = idx & 15;
      As[kq][m] = (k0 + kq < K) ? ldval(A[(size_t)(bm + m)*lda + k0 + kq]) : 0.f;
      int kk = idx >> 6, n = idx & 63;
      Bs[kk][n] = (k0 + kk < K) ? Wm[(size_t)(k0 + kk)*N + bn + n] : 0.f;
    }
    __syncthreads();
#pragma unroll
    for (int kq = 0; kq < 16; kq++){
      float av[4], bv[4];
#pragma unroll
      for (int i = 0; i < 4; i++) av[i] = As[kq][ty*4 + i];
#pragma unroll
      for (int j = 0; j < 4; j++) bv[j] = Bs[kq][tx*4 + j];
#pragma unroll
      for (int i = 0; i < 4; i++)
#pragma unroll
        for (int j = 0; j < 4; j++) acc[i][j] += av[i]*bv[j];
    }
    __syncthreads();
  }
#pragma unroll
  for (int i = 0; i < 4; i++){
    int m = bm + ty*4 + i;
#pragma unroll
    for (int j = 0; j < 4; j++){
      int n = bn + tx*4 + j;
      float v = acc[i][j] + bias[n];
      if (resid) v += resid[(size_t)m*ldc + n];
      stval(&Cc[(size_t)m*ldc + n], v);
    }
  }
}

// MFMA GEMM: 128x128 macro tile, 4 waves 2x2, each 64x64 via 4x4 mfma_16x16x32.
template<typename TC>
__global__ __launch_bounds__(256) void gemm_mfma(
    const u16* __restrict__ A, int lda,
    const u16* __restrict__ WT,
    const float* __restrict__ bias,
    TC* __restrict__ Cc, int ldc, const float* __restrict__ resid,
    int N, int K)
{
  __shared__ alignas(16) u16 As[128*40];
  __shared__ alignas(16) u16 Bs[128*40];
  const int bm = blockIdx.y * 128, bn = blockIdx.x * 128;
  const int tid = threadIdx.x;
  const int w = tid >> 6, lane = tid & 63, lm = lane & 15, q = lane >> 4;
  const int wm = w >> 1, wn = w & 1;
  float4v acc[4][4] = {};
  for (int k0 = 0; k0 < K; k0 += 32){
    __syncthreads();
#pragma unroll
    for (int c = tid; c < 512; c += 256){
      int r = c >> 2, ch = c & 3;
      *(uint4*)&As[r*40 + ch*8] = *(const uint4*)&A[(size_t)(bm + r)*lda + k0 + ch*8];
      int n = bn + r;
      uint4 bv = {0u,0u,0u,0u};
      if (n < N) bv = *(const uint4*)&WT[(size_t)n*K + k0 + ch*8];
      *(uint4*)&Bs[r*40 + ch*8] = bv;
    }
    __syncthreads();
    short8 a[4], b[4];
#pragma unroll
    for (int i = 0; i < 4; i++)
      a[i] = *(const short8*)&As[(wm*64 + i*16 + lm)*40 + q*8];
#pragma unroll
    for (int j = 0; j < 4; j++)
      b[j] = *(const short8*)&Bs[(wn*64 + j*16 + lm)*40 + q*8];
#pragma unroll
    for (int i = 0; i < 4; i++)
#pragma unroll
      for (int j = 0; j < 4; j++)
        acc[i][j] = __builtin_amdgcn_mfma_f32_16x16x32_bf16(a[i], b[j], acc[i][j], 0, 0, 0);
  }
#pragma unroll
  for (int i = 0; i < 4; i++){
#pragma unroll
    for (int j = 0; j < 4; j++){
      int col = bn + wn*64 + j*16 + lm;
      if (col < N){
#pragma unroll
        for (int r = 0; r < 4; r++){
          int row = bm + wm*64 + i*16 + q*4 + r;
          float v = acc[i][j][r] + bias[col];
          if (resid) v += resid[(size_t)row*ldc + col];
          stval(&Cc[(size_t)row*ldc + col], v);
        }
      }
    }
  }
}

// LayerNorm: one wave per row, float4 loads, shuffle-only reductions.
__global__ __launch_bounds__(256) void ln_kernel(const float* __restrict__ Xin,
    const float* __restrict__ g, const float* __restrict__ b,
    u16* __restrict__ out, float eps){
  int t = blockIdx.x*4 + (threadIdx.x >> 6);
  int e = threadIdx.x & 63;
  float4 v = *(const float4*)&Xin[(size_t)t*256 + e*4];
  float su = v.x + v.y + v.z + v.w;
#pragma unroll
  for (int o = 32; o > 0; o >>= 1) su += __shfl_xor(su, o, 64);
  float mu = su * (1.f/256.f);
  float d0 = v.x - mu, d1 = v.y - mu, d2 = v.z - mu, d3 = v.w - mu;
  float sq = d0*d0 + d1*d1 + d2*d2 + d3*d3;
#pragma unroll
  for (int o = 32; o > 0; o >>= 1) sq += __shfl_xor(sq, o, 64);
  float rstd = rsqrtf(sq * (1.f/256.f) + eps);
  float4 gv = *(const float4*)&g[e*4];
  float4 bv = *(const float4*)&b[e*4];
  ushort4 o4;
  o4.x = f2b(d0*rstd*gv.x + bv.x);
  o4.y = f2b(d1*rstd*gv.y + bv.y);
  o4.z = f2b(d2*rstd*gv.z + bv.z);
  o4.w = f2b(d3*rstd*gv.w + bv.w);
  *(ushort4*)&out[(size_t)t*256 + e*4] = o4;
}

// depthwise causal conv (K=4) + silu, ushort8 vectorized (8 channels/thread)
__global__ __launch_bounds__(256) void conv_silu_kernel(const u16* __restrict__ Xc, int ldx, int C,
    const float* __restrict__ w, const float* __restrict__ bias, u16* __restrict__ Y){
  int nc = C >> 3;
  long long gid = (long long)blockIdx.x * 256 + threadIdx.x;   // T*nc
  int c8 = (int)(gid % nc) * 8; long long t = gid / nc;
  int s = (int)(t & 255);
  float acc[8];
#pragma unroll
  for (int i = 0; i < 8; i++) acc[i] = bias[c8 + i];
#pragma unroll
  for (int j = 0; j < 4; j++){
    int so = s - 3 + j;
    if (so >= 0){
      ushort8v xv = *(const ushort8v*)&Xc[(size_t)(t - 3 + j)*ldx + c8];
#pragma unroll
      for (int i = 0; i < 8; i++) acc[i] += b2f(xv[i]) * w[j*C + c8 + i];
    }
  }
  ushort8v o8;
#pragma unroll
  for (int i = 0; i < 8; i++) o8[i] = f2b(acc[i] / (1.f + __expf(-acc[i])));
  *(ushort8v*)&Y[(size_t)t*C + c8] = o8;
}

// ipre/fpre: gin=[q|k|v] (T x 1536) @ Wi/Wf (1536 x 4), ushort8 inner loads
__global__ __launch_bounds__(256) void gates_kernel(
    const u16* __restrict__ Q, const u16* __restrict__ Kb, const u16* __restrict__ V,
    const float* __restrict__ Wi, const float* __restrict__ bi,
    const float* __restrict__ Wf, const float* __restrict__ bf,
    float* __restrict__ IP, float* __restrict__ FP){
  int t = blockIdx.x; int tid = threadIdx.x;
  int o = tid & 7, seg = tid >> 3;
  int b = t >> 8, s = t & 255;
  int g = o & 3;
  const float* Wg = (o >= 4) ? Wf : Wi;
  float part = 0.f;
#pragma unroll
  for (int i = 0; i < 6; i++){
    int k8 = seg*48 + i*8;
    const u16* src; int off;
    if (k8 < 512){ src = Q; off = k8; }
    else if (k8 < 1024){ src = Kb; off = k8 - 512; }
    else { src = V; off = k8 - 1024; }
    ushort8v gv = *(const ushort8v*)&src[(size_t)t*512 + off];
#pragma unroll
    for (int j = 0; j < 8; j++) part += b2f(gv[j]) * Wg[(k8 + j)*4 + g];
  }
  __shared__ float red[256];
  red[tid] = part; __syncthreads();
  if (tid < 8){
    float tot = 0.f;
    for (int ss = 0; ss < 32; ss++) tot += red[ss*8 + tid];
    int gg = tid & 3;
    if (tid < 4) IP[(b*4 + gg)*256 + s] = tot + bi[gg];
    else         FP[(b*4 + gg)*256 + s] = tot + bf[gg];
  }
}

// per (b,h): F=cumsum(logsigmoid(fpre)); G=ipre-F; M=cummax(G)
__global__ __launch_bounds__(256) void fscan_kernel(const float* __restrict__ IP,
    const float* __restrict__ FP, float* __restrict__ Fo, float* __restrict__ Go,
    float* __restrict__ Mo){
  int bh = blockIdx.x; int s = threadIdx.x;
  int idx = bh*256 + s;
  __shared__ float buf[256];
  float fp = FP[idx];
  float lfg = fminf(fp, 0.f) - log1pf(expf(-fabsf(fp)));
  float v = lfg;
  buf[s] = v; __syncthreads();
  for (int off = 1; off < 256; off <<= 1){
    float tv = (s >= off) ? buf[s - off] : 0.f;
    __syncthreads();
    v += tv; buf[s] = v;
    __syncthreads();
  }
  float Fv = v;
  float g = IP[idx] - Fv;
  float mv = g;
  buf[s] = mv; __syncthreads();
  for (int off = 1; off < 256; off <<= 1){
    float tv = (s >= off) ? buf[s - off] : -3.0e38f;
    __syncthreads();
    mv = fmaxf(mv, tv); buf[s] = mv;
    __syncthreads();
  }
  Fo[idx] = Fv; Go[idx] = g; Mo[idx] = mv;
}

// Fused MFMA mLSTM attention (unchanged).
__global__ __launch_bounds__(256) void attn_kernel(
    const u16* __restrict__ Q, const u16* __restrict__ Kb, const u16* __restrict__ V,
    const float* __restrict__ G, const float* __restrict__ Mx, const float* __restrict__ F,
    const u16* __restrict__ Ab, const u16* __restrict__ UPb,
    const float* __restrict__ ng, const float* __restrict__ nb,
    const float* __restrict__ skip, u16* __restrict__ Yb)
{
  int bh = blockIdx.y, b = bh >> 2, h = bh & 3;
  int tt = blockIdx.x, t0 = tt * 64;
  int tid = threadIdx.x;
  int w = tid >> 6, lane = tid & 63, lm = lane & 15, q = lane >> 4;
  int gbase = bh * 256;

  __shared__ alignas(16) u16 Qs[64*136];
  __shared__ alignas(16) u16 Ks[64*136];
  __shared__ alignas(16) u16 Vt[128*72];
  __shared__ alignas(16) u16 Ps[64*72];
  __shared__ float rs[64];

#pragma unroll
  for (int c = tid; c < 1024; c += 256){
    int r = c >> 4, ch = c & 15;
    *(uint4*)&Qs[r*136 + ch*8] =
      *(const uint4*)&Q[((size_t)(b*256 + t0 + r))*512 + h*128 + ch*8];
  }
  if (tid < 64) rs[tid] = 0.f;

  float mrow[4];
#pragma unroll
  for (int r = 0; r < 4; r++) mrow[r] = Mx[gbase + t0 + w*16 + q*4 + r];

  float4v acc2[8] = {};
  const float scale = 0.08838834764831845f;

  for (int ss = 0; ss <= tt; ss++){
    int s0 = ss * 64;
    __syncthreads();
#pragma unroll
    for (int c = tid; c < 1024; c += 256){
      int r = c >> 4, ch = c & 15;
      *(uint4*)&Ks[r*136 + ch*8] =
        *(const uint4*)&Kb[((size_t)(b*256 + s0 + r))*512 + h*128 + ch*8];
    }
#pragma unroll
    for (int c = tid; c < 1024; c += 256){
      int sl = c & 63, db = c >> 6;
      ushort8v v = *(const ushort8v*)&V[((size_t)(b*256 + s0 + sl))*512 + h*128 + db*8];
#pragma unroll
      for (int j = 0; j < 8; j++) Vt[(db*8 + j)*72 + sl] = v[j];
    }
    __syncthreads();
    float4v sacc[4] = {};
#pragma unroll
    for (int k0 = 0; k0 < 128; k0 += 32){
      short8 a = *(const short8*)&Qs[(w*16 + lm)*136 + k0 + q*8];
#pragma unroll
      for (int j = 0; j < 4; j++){
        short8 bb = *(const short8*)&Ks[(j*16 + lm)*136 + k0 + q*8];
        sacc[j] = __builtin_amdgcn_mfma_f32_16x16x32_bf16(a, bb, sacc[j], 0, 0, 0);
      }
    }
    float rp[4] = {0.f, 0.f, 0.f, 0.f};
#pragma unroll
    for (int j = 0; j < 4; j++){
      int scol = s0 + j*16 + lm;
      float gq = G[gbase + scol];
#pragma unroll
      for (int r = 0; r < 4; r++){
        int trow = t0 + w*16 + q*4 + r;
        float cval = (scol <= trow) ? sacc[j][r]*scale*__expf(gq - mrow[r]) : 0.f;
        Ps[(w*16 + q*4 + r)*72 + j*16 + lm] = f2b(cval);
        rp[r] += cval;
      }
    }
#pragma unroll
    for (int r = 0; r < 4; r++){
#pragma unroll
      for (int m = 1; m < 16; m <<= 1) rp[r] += __shfl_xor(rp[r], m, 16);
      if (lm == 0) rs[w*16 + q*4 + r] += rp[r];
    }
#pragma unroll
    for (int k0 = 0; k0 < 64; k0 += 32){
      short8 a = *(const short8*)&Ps[(w*16 + lm)*72 + k0 + q*8];
#pragma unroll
      for (int jd = 0; jd < 8; jd++){
        short8 bb = *(const short8*)&Vt[(jd*16 + lm)*72 + k0 + q*8];
        acc2[jd] = __builtin_amdgcn_mfma_f32_16x16x32_bf16(a, bb, acc2[jd], 0, 0, 0);
      }
    }
  }
  __syncthreads();
#pragma unroll
  for (int r = 0; r < 4; r++){
    int rl = w*16 + q*4 + r;
    int t = t0 + rl;
    float Fv = F[gbase + t];
    float nrm = fmaxf(fabsf(rs[rl]), __expf(-(Fv + mrow[r])));
    float inv = 1.f / nrm;
    float vv[8];
    float su = 0.f;
#pragma unroll
    for (int jd = 0; jd < 8; jd++){ vv[jd] = acc2[jd][r]*inv; su += vv[jd]; }
#pragma unroll
    for (int m = 1; m < 16; m <<= 1) su += __shfl_xor(su, m, 16);
    float mu = su * (1.f/128.f);
    float sq = 0.f;
#pragma unroll
    for (int jd = 0; jd < 8; jd++){ vv[jd] -= mu; sq += vv[jd]*vv[jd]; }
#pragma unroll
    for (int m = 1; m < 16; m <<= 1) sq += __shfl_xor(sq, m, 16);
    float rstd = rsqrtf(sq * (1.f/128.f) + 1e-6f);
#pragma unroll
    for (int jd = 0; jd < 8; jd++){
      int c = h*128 + jd*16 + lm;
      float hv = vv[jd]*rstd*ng[c] + nb[c];
      float av = b2f(Ab[(size_t)t*512 + c]);
      float zg = b2f(UPb[(size_t)t*1024 + 512 + c]);
      float sz = zg / (1.f + __expf(-zg));
      Yb[(size_t)t*512 + c] = f2b((hv + skip[c]*av)*sz);
    }
  }
}

// sLSTM recurrence: 5 waves per (b,h), chunked register preload (16 steps).
//  - waves 0..3: matvec split over d (16 each); each wave preloads ITS gate
//    stream (w0->IT w1->FT w2->ZT w3->OT) 16 steps at a time into registers
//    and adds gch[j] into component w of its float4 partial. Steady-state
//    steps have ZERO vmem -> __syncthreads' implicit vmcnt(0) drain is gone.
//  - wave 4: processes chunk c-1 during chunk c (hbuf = 32-slot ring, halves
//    disjoint); Xr rows chunk-preloaded, 16 stores batched per chunk; headnorm
//    reduction via DPP row_shr/row_bcast (+readlane 63) instead of shfl_xor.
//  - barrier count identical on both paths: 257.
__global__ __launch_bounds__(320) void scan_kernel(
    const float* __restrict__ IT, const float* __restrict__ FT,
    const float* __restrict__ ZT, const float* __restrict__ OT,
    const float* __restrict__ Ri, const float* __restrict__ Rf,
    const float* __restrict__ Rz, const float* __restrict__ Ro,
    const float* __restrict__ sng, const float* __restrict__ snb,
    float* __restrict__ Xr){
  int bh = blockIdx.x; int b = bh >> 2, h = bh & 3;
  int e = threadIdx.x & 63;
  int w = threadIdx.x >> 6;                 // 0..4, wave-uniform
  __shared__ float4 part[2][4][64];         // [j&1][wave][e] = 4 gate partials
  __shared__ float hbuf[32][64];            // ring: slot = (16c+j) & 31
  size_t rowbase = ((size_t)b*256)*256 + h*64 + e;

  if (w < 4){
    // R fragments: rX[k] = R_X[h][w*16+k][e]
    float r0[16], r1[16], r2[16], r3[16];
    const float* Rp0 = Ri + h*4096 + w*1024;
    const float* Rp1 = Rf + h*4096 + w*1024;
    const float* Rp2 = Rz + h*4096 + w*1024;
    const float* Rp3 = Ro + h*4096 + w*1024;
#pragma unroll
    for (int d = 0; d < 16; d++){
      r0[d] = Rp0[d*64 + e];
      r1[d] = Rp1[d*64 + e];
      r2[d] = Rp2[d*64 + e];
      r3[d] = Rp3[d*64 + e];
    }
    const float* Gp = (w == 0) ? IT : (w == 1) ? FT : (w == 2) ? ZT : OT;
    float hS = 0.f, cS = 0.f, nS = 0.f, mS = 0.f;
    for (int c = 0; c < 16; c++){
      // chunk preload: this wave's gate stream, 16 steps (drains once/chunk)
      float gch[16];
#pragma unroll
      for (int j = 0; j < 16; j++)
        gch[j] = Gp[rowbase + (size_t)(c*16 + j)*256];
#pragma unroll
      for (int j = 0; j < 16; j++){
        // phase A: partial matvec over this wave's 16 d's (8 chains)
        float ai0 = 0.f, ai1 = 0.f, af0 = 0.f, af1 = 0.f;
        float az0 = 0.f, az1 = 0.f, ao0 = 0.f, ao1 = 0.f;
#pragma unroll
        for (int k = 0; k < 16; k += 2){
          float h0 = __builtin_bit_cast(float,
              __builtin_amdgcn_readlane(__builtin_bit_cast(int, hS), w*16 + k));
          float h1 = __builtin_bit_cast(float,
              __builtin_amdgcn_readlane(__builtin_bit_cast(int, hS), w*16 + k + 1));
          ai0 += h0*r0[k]; ai1 += h1*r0[k+1];
          af0 += h0*r1[k]; af1 += h1*r1[k+1];
          az0 += h0*r2[k]; az1 += h1*r2[k+1];
          ao0 += h0*r3[k]; ao1 += h1*r3[k+1];
        }
        float4 p;
        p.x = ai0 + ai1; p.y = af0 + af1; p.z = az0 + az1; p.w = ao0 + ao1;
        float g = gch[j];
        if      (w == 0) p.x += g;
        else if (w == 1) p.y += g;
        else if (w == 2) p.z += g;
        else             p.w += g;
        part[j & 1][w][e] = p;
        __syncthreads();
        // phase B: replicated reduce + scalar tail (bitwise identical, 4 waves)
        float4 q0 = part[j & 1][0][e];
        float4 q1 = part[j & 1][1][e];
        float4 q2 = part[j & 1][2][e];
        float4 q3 = part[j & 1][3][e];
        float ip = (q0.x + q1.x) + (q2.x + q3.x);
        float fp = (q0.y + q1.y) + (q2.y + q3.y);
        float zr = (q0.z + q1.z) + (q2.z + q3.z);
        float og = (q0.w + q1.w) + (q2.w + q3.w);
        float zp = 1.f - 2.f*__builtin_amdgcn_rcpf(__expf(2.f*zr) + 1.f);
        float op = __builtin_amdgcn_rcpf(1.f + __expf(-og));
        float mn = fmaxf(fp + mS, ip);
        float ig = __expf(ip - mn);
        float fg = __expf(fp + mS - mn);
        cS = fg*cS + ig*zp;
        nS = fg*nS + ig;
        mS = mn;
        hS = op * cS * __builtin_amdgcn_rcpf(nS);
        if (w == 1) hbuf[((c & 1) << 4) | j][e] = hS;
      }
    }
    __syncthreads();  // pairs with wave 4's epilogue barrier
  } else {
    // output wave: one chunk behind; headnorm via DPP; batched loads/stores
    float gw = sng[h*64 + e], bw = snb[h*64 + e];
    for (int c = 0; c < 16; c++){
      float xch[16], och[16];
      if (c > 0){
#pragma unroll
        for (int j = 0; j < 16; j++)
          xch[j] = Xr[rowbase + (size_t)((c - 1)*16 + j)*256];
      }
#pragma unroll
      for (int j = 0; j < 16; j++){
        if (c > 0){
          float hv = hbuf[(((c - 1) & 1) << 4) | j][e];
          float su, sq;
          dpp_sum2(hv, hv*hv, su, sq);
          float mu = su * (1.f/64.f);
          float var = fmaxf(sq * (1.f/64.f) - mu*mu, 0.f);
          och[j] = xch[j] + (hv - mu) * rsqrtf(var + 1e-6f) * gw + bw;
          if (j == 15){
#pragma unroll
            for (int jj = 0; jj < 16; jj++)
              Xr[rowbase + (size_t)((c - 1)*16 + jj)*256] = och[jj];
          }
        }
        __syncthreads();
      }
    }
    __syncthreads();
    // epilogue: chunk 15 (rows 240..255; hbuf slots 16|j)
    float xch[16];
#pragma unroll
    for (int j = 0; j < 16; j++)
      xch[j] = Xr[rowbase + (size_t)(240 + j)*256];
#pragma unroll
    for (int j = 0; j < 16; j++){
      float hv = hbuf[16 | j][e];
      float su, sq;
      dpp_sum2(hv, hv*hv, su, sq);
      float mu = su * (1.f/64.f);
      float var = fmaxf(sq * (1.f/64.f) - mu*mu, 0.f);
      Xr[rowbase + (size_t)(240 + j)*256] =
          xch[j] + (hv - mu) * rsqrtf(var + 1e-6f) * gw + bw;
    }
  }
}

// FFN activation: P = gelu_tanh(g) * u, ushort8 vectorized
__global__ __launch_bounds__(256) void ffn_act_kernel(const u16* __restrict__ GU,
                                                      u16* __restrict__ P){
  long long gid = (long long)blockIdx.x * 256 + threadIdx.x;   // T*44
  int j8 = (int)(gid % 44) * 8; long long t = gid / 44;
  ushort8v gv = *(const ushort8v*)&GU[(size_t)t*704 + j8];
  ushort8v uv = *(const ushort8v*)&GU[(size_t)t*704 + 352 + j8];
  ushort8v o8;
#pragma unroll
  for (int i = 0; i < 8; i++){
    float g = b2f(gv[i]);
    float u = b2f(uv[i]);
    float inner = 0.7978845608028654f * (g + 0.044715f*g*g*g);
    float gel = 0.5f * g * (1.f + tanhf(inner));
    o8[i] = f2b(gel * u);
  }
  *(ushort8v*)&P[(size_t)t*352 + j8] = o8;
}

// output head: relu(last@W1+b1)@W2+b2, write in detected dtype
__global__ __launch_bounds__(64) void head_kernel(const float* __restrict__ X,
    const float* __restrict__ W1, const float* __restrict__ b1,
    const float* __restrict__ W2, const float* __restrict__ b2,
    void* out, const int* __restrict__ flag){
  int b = blockIdx.x, j = threadIdx.x;
  __shared__ float L[256];
  __shared__ float H1[64];
  for (int i = j; i < 256; i += 64) L[i] = X[((size_t)(b*256 + 255))*256 + i];
  __syncthreads();
  float acc = b1[j];
  for (int d = 0; d < 256; d++) acc += L[d] * W1[d*64 + j];
  H1[j] = fmaxf(acc, 0.f);
  __syncthreads();
  if (j < 3){
    float o = b2[j];
    for (int k2 = 0; k2 < 64; k2++) o += H1[k2] * W2[k2*3 + j];
    if (*flag) ((u16*)out)[b*3 + j] = f2b(o);
    else       ((float*)out)[b*3 + j] = o;
  }
}

// ----------------------------- launch --------------------------------------
extern "C" void kernel_launch(void* const* d_in, const int* in_sizes, int n_in,
                              void* d_out, int out_size, void* d_ws, size_t ws_size,
                              hipStream_t stream)
{
  if (n_in != IN_N) return;
  for (int i = 0; i < IN_N; i++) if ((long long)in_sizes[i] != IN_SIZES[i]) return;
  if (ws_size < (size_t)WS_END * 4) return;
  if (out_size != 384) return;

  float* ws = (float*)d_ws;
  float* cv = ws;
  auto cvp = [&](int i){ return cv + CVOFF.off[i]; };

  int*   flag = (int*)(ws + OFF_FLAG);
  float* IP   = ws + OFF_IP;
  float* FP   = ws + OFF_FP;
  float* Fb   = ws + OFF_F;
  float* Gb   = ws + OFF_G;
  float* Mb   = ws + OFF_M;
  float* X    = ws + OFF_X;
  u16*   XNb  = (u16*)(ws + OFF_XN);
  u16*   UPb  = (u16*)(ws + OFF_UP);
  u16*   Ab   = (u16*)(ws + OFF_A);
  u16*   Qb   = (u16*)(ws + OFF_Q);
  u16*   Kbb  = (u16*)(ws + OFF_K);
  u16*   Vb   = (u16*)(ws + OFF_V);
  u16*   WTb  = (u16*)(ws + OFF_WT);
  // overlays (lifetimes disjoint):
  float* CAT = ws + OFF_V;
  u16*   Yb  = Qb;
  u16*   ACb = Ab;
  float* ITf = ws + OFF_K;
  float* FTf = ws + OFF_V;
  float* ZTf = ws + OFF_Q;
  float* OTf = ws + OFF_UP;
  u16*   GUb = UPb;
  u16*   Pb  = Ab;

  auto wt = [&](int widx){ return WTb + WTO[widx]; };

  InPtrs ptrs;
  for (int i = 0; i < IN_N; i++) ptrs.p[i] = d_in[i];

  const int M = 32768;
  detect_kernel<<<1, 64, 0, stream>>>(d_in[7], flag);
  int cvblocks = (int)((CV_TOTAL + 255) / 256);
  convert_kernel<<<cvblocks, 256, 0, stream>>>(ptrs, cv, flag);
  wtrans_kernel<<<dim3(32, 16, 11), 256, 0, stream>>>(ptrs, WTb, flag);
  cat_kernel<<<5120, 256, 0, stream>>>(cvp(0), (const int*)d_in[1], (const int*)d_in[2],
                                       cvp(3), cvp(4), CAT);
  gemm_kernel<float, float><<<dim3(4, 512), 256, 0, stream>>>(CAT, 40, cvp(5), cvp(6),
      X, 256, nullptr, M, 256, 40);
  // ---- mLSTM block ----
  ln_kernel<<<8192, 256, 0, stream>>>(X, cvp(7), cvp(8), XNb, 1e-5f);
  gemm_mfma<u16><<<dim3(8, 256), 256, 0, stream>>>(XNb, 256, wt(0), cvp(10),
      UPb, 1024, nullptr, 1024, 256);
  conv_silu_kernel<<<8192, 256, 0, stream>>>(UPb, 1024, 512, cvp(11), cvp(12), Ab);
  gemm_mfma<u16><<<dim3(4, 256), 256, 0, stream>>>(Ab, 512, wt(1), cvp(14),
      Qb, 512, nullptr, 512, 512);
  gemm_mfma<u16><<<dim3(4, 256), 256, 0, stream>>>(Ab, 512, wt(2), cvp(16),
      Kbb, 512, nullptr, 512, 512);
  gemm_mfma<u16><<<dim3(4, 256), 256, 0, stream>>>(UPb, 1024, wt(3), cvp(18),
      Vb, 512, nullptr, 512, 512);
  gates_kernel<<<M, 256, 0, stream>>>(Qb, Kbb, Vb, cvp(19), cvp(20), cvp(21), cvp(22), IP, FP);
  fscan_kernel<<<512, 256, 0, stream>>>(IP, FP, Fb, Gb, Mb);
  attn_kernel<<<dim3(4, 512), 256, 0, stream>>>(Qb, Kbb, Vb, Gb, Mb, Fb,
      Ab, UPb, cvp(24), cvp(25), cvp(23), Yb);
  gemm_mfma<float><<<dim3(2, 256), 256, 0, stream>>>(Yb, 512, wt(4), cvp(27),
      X, 256, X, 256, 512);
  // ---- sLSTM block ----
  ln_kernel<<<8192, 256, 0, stream>>>(X, cvp(28), cvp(29), XNb, 1e-5f);
  conv_silu_kernel<<<4096, 256, 0, stream>>>(XNb, 256, 256, cvp(30), cvp(31), ACb);
  gemm_mfma<float><<<dim3(2, 256), 256, 0, stream>>>(ACb, 256, wt(5), cvp(33),
      ITf, 256, nullptr, 256, 256);
  gemm_mfma<float><<<dim3(2, 256), 256, 0, stream>>>(ACb, 256, wt(6), cvp(35),
      FTf, 256, nullptr, 256, 256);
  gemm_mfma<float><<<dim3(2, 256), 256, 0, stream>>>(XNb, 256, wt(7), cvp(37),
      ZTf, 256, nullptr, 256, 256);
  gemm_mfma<float><<<dim3(2, 256), 256, 0, stream>>>(XNb, 256, wt(8), cvp(39),
      OTf, 256, nullptr, 256, 256);
  scan_kernel<<<512, 320, 0, stream>>>(ITf, FTf, ZTf, OTf, cvp(40), cvp(41), cvp(42), cvp(43),
      cvp(44), cvp(45), X);
  // ---- FFN ----
  ln_kernel<<<8192, 256, 0, stream>>>(X, cvp(46), cvp(47), XNb, 1e-5f);
  gemm_mfma<u16><<<dim3(6, 256), 256, 0, stream>>>(XNb, 256, wt(9), cvp(49),
      GUb, 704, nullptr, 704, 256);
  ffn_act_kernel<<<5632, 256, 0, stream>>>(GUb, Pb);
  gemm_mfma<float><<<dim3(2, 256), 256, 0, stream>>>(Pb, 352, wt(10), cvp(51),
      X, 256, X, 256, 352);
  // ---- head ----
  head_kernel<<<128, 64, 0, stream>>>(X, cvp(52), cvp(53), cvp(54), cvp(55), d_out, flag);
}

// Round 5
// 1151.948 us; speedup vs baseline: 1.0093x; 1.0093x over previous
//
#include <hip/hip_runtime.h>
#include <cstdint>
#include <cstddef>

// ---------------------------------------------------------------------------
// Model_xLSTM: B=128 S=256 NF=32 E=4 D=256 H=4 DI=512 DHM=128 DHS=64 K=4 FF=352
// Round 10 (= R9 resubmit verbatim; R9 died to GPUAcquisitionTimeout before
// staging -- pure infra, no kernel evidence. R8's ambiguous container failure
// now also more likely infra):
//  * scan: R6 per-step streaming structure, raw s_barrier + explicit
//    lgkmcnt(0) (no __syncthreads) so gate/Xr loads stay in flight across
//    barriers. sched_barrier(0) on BOTH sides of s_barrier (rule-18 both
//    variants). Each compute wave streams its OWN gate column 2 steps ahead;
//    wave 4 does DPP headnorm + per-step Xr read-add-write, one step behind.
//  * sLSTM gate GEMMs merged 4 -> 2 (N=512): wt(5)|wt(6) and wt(7)|wt(8)
//    contiguous in WT arena; cvp(33)=[s_bi|s_bf], cvp(37)=[s_bz|s_bo]
//    contiguous in cv. Outputs to combined [T x 512] fp32 buffers
//    (IT|FT spans OFF_K+OFF_V, ZT|OT fills OFF_UP); scan reads stride 512.
// Rest frozen (R4/R5).
// ---------------------------------------------------------------------------

using u16 = unsigned short;
using u32 = unsigned int;

typedef __attribute__((ext_vector_type(8))) short short8;
typedef __attribute__((ext_vector_type(8))) unsigned short ushort8v;
typedef __attribute__((ext_vector_type(4))) float float4v;

#define DEVINL __device__ __forceinline__

DEVINL float b2f(u16 u){ u32 x = ((u32)u) << 16; return __builtin_bit_cast(float, x); }
DEVINL u16 f2b(float f){
  u32 x = __builtin_bit_cast(u32, f);
  u32 r = x + 0x7FFFu + ((x >> 16) & 1u);   // RTNE
  return (u16)(r >> 16);
}
DEVINL float ldval(float x){ return x; }
DEVINL float ldval(u16 x){ return b2f(x); }
DEVINL void stval(float* p, float v){ *p = v; }
DEVINL void stval(u16* p, float v){ *p = f2b(v); }

// barrier with LDS-only wait (keeps vmem loads in flight across the barrier);
// sched_barrier on BOTH sides: no LDS op may sink below the waitcnt nor be
// hoisted above the s_barrier.
DEVINL void lds_barrier(){
  asm volatile("s_waitcnt lgkmcnt(0)" ::: "memory");
  __builtin_amdgcn_sched_barrier(0);
  __builtin_amdgcn_s_barrier();
  __builtin_amdgcn_sched_barrier(0);
}

// dual-chain 64-lane sum via DPP (gfx9 row ops), results broadcast via lane 63
DEVINL void dpp_sum2(float a, float b, float& oa, float& ob){
  int xa, xb;
  xa = __builtin_amdgcn_update_dpp(0, __builtin_bit_cast(int, a), 0x111, 0xf, 0xf, true);
  xb = __builtin_amdgcn_update_dpp(0, __builtin_bit_cast(int, b), 0x111, 0xf, 0xf, true);
  a += __builtin_bit_cast(float, xa); b += __builtin_bit_cast(float, xb);
  xa = __builtin_amdgcn_update_dpp(0, __builtin_bit_cast(int, a), 0x112, 0xf, 0xf, true);
  xb = __builtin_amdgcn_update_dpp(0, __builtin_bit_cast(int, b), 0x112, 0xf, 0xf, true);
  a += __builtin_bit_cast(float, xa); b += __builtin_bit_cast(float, xb);
  xa = __builtin_amdgcn_update_dpp(0, __builtin_bit_cast(int, a), 0x114, 0xf, 0xf, true);
  xb = __builtin_amdgcn_update_dpp(0, __builtin_bit_cast(int, b), 0x114, 0xf, 0xf, true);
  a += __builtin_bit_cast(float, xa); b += __builtin_bit_cast(float, xb);
  xa = __builtin_amdgcn_update_dpp(0, __builtin_bit_cast(int, a), 0x118, 0xf, 0xf, true);
  xb = __builtin_amdgcn_update_dpp(0, __builtin_bit_cast(int, b), 0x118, 0xf, 0xf, true);
  a += __builtin_bit_cast(float, xa); b += __builtin_bit_cast(float, xb);
  xa = __builtin_amdgcn_update_dpp(0, __builtin_bit_cast(int, a), 0x142, 0xf, 0xf, true);
  xb = __builtin_amdgcn_update_dpp(0, __builtin_bit_cast(int, b), 0x142, 0xf, 0xf, true);
  a += __builtin_bit_cast(float, xa); b += __builtin_bit_cast(float, xb);
  xa = __builtin_amdgcn_update_dpp(0, __builtin_bit_cast(int, a), 0x143, 0xf, 0xf, true);
  xb = __builtin_amdgcn_update_dpp(0, __builtin_bit_cast(int, b), 0x143, 0xf, 0xf, true);
  a += __builtin_bit_cast(float, xa); b += __builtin_bit_cast(float, xb);
  oa = __builtin_bit_cast(float, __builtin_amdgcn_readlane(__builtin_bit_cast(int, a), 63));
  ob = __builtin_bit_cast(float, __builtin_amdgcn_readlane(__builtin_bit_cast(int, b), 63));
}

// ----------------------------- input table ---------------------------------
constexpr int IN_N = 56;
constexpr long long IN_SIZES[IN_N] = {
  1048576, 128, 128, 404, 28, 10240, 256, 256, 256,
  262144, 1024, 2048, 512,
  262144, 512, 262144, 512, 262144, 512,
  6144, 4, 6144, 4,
  512, 512, 512, 131072, 256,
  256, 256, 1024, 256,
  65536, 256, 65536, 256, 65536, 256, 65536, 256,
  16384, 16384, 16384, 16384,
  256, 256,
  256, 256, 180224, 704, 90112, 256,
  16384, 64, 192, 3 };

constexpr bool is_wt_input(int i){
  return i==9 || i==13 || i==15 || i==17 || i==26 || i==32 || i==34 || i==36
      || i==38 || i==48 || i==50;
}

struct CvOff { long long off[IN_N+1]; };
constexpr CvOff make_off(){
  CvOff o{};
  long long a = 0;
  for (int i = 0; i < IN_N; i++){
    o.off[i] = a;
    long long s = IN_SIZES[i];
    if (i == 1 || i == 2 || is_wt_input(i)) s = 0;
    a += s;
  }
  o.off[IN_N] = a;
  return o;
}
constexpr CvOff CVOFF = make_off();
constexpr long long CV_TOTAL = CVOFF.off[IN_N];

// transposed-weight table
constexpr int WT_NW = 11;
constexpr int WTB_IN[WT_NW] = {9, 13, 15, 17, 26, 32, 34, 36, 38, 48, 50};
constexpr int WTB_K[WT_NW]  = {256,512,512,512,512,256,256,256,256,256,352};
constexpr int WTB_N[WT_NW]  = {1024,512,512,512,256,256,256,256,256,704,256};
constexpr long long WTO[WT_NW+1] = {0, 262144, 524288, 786432, 1048576, 1179648,
  1245184, 1310720, 1376256, 1441792, 1622016, 1712128};
constexpr long long WT_ELEMS = WTO[WT_NW];

// ----------------------------- ws layout (float units) ---------------------
constexpr long long alignup(long long x){ return ((x + 255) / 256) * 256; }
constexpr long long TOK = 32768;            // B*S
constexpr long long OFF_FLAG = alignup(CV_TOTAL);
constexpr long long OFF_IP  = OFF_FLAG + 64;
constexpr long long OFF_FP  = OFF_IP  + 131072;
constexpr long long OFF_F   = OFF_FP  + 131072;
constexpr long long OFF_G   = OFF_F   + 131072;
constexpr long long OFF_M   = OFF_G   + 131072;
constexpr long long OFF_X   = OFF_M   + 131072;           // T x 256 fp32
constexpr long long OFF_XN  = OFF_X   + TOK*256;          // T x 256 bf16
constexpr long long OFF_UP  = OFF_XN  + TOK*128;          // T x 1024 bf16 (xm|zg / ZT|OT fp32)
constexpr long long OFF_A   = OFF_UP  + TOK*512;          // T x 512 bf16 (a / AC / P)
constexpr long long OFF_Q   = OFF_A   + TOK*256;          // T x 512 bf16 (q / Y)
constexpr long long OFF_K   = OFF_Q   + TOK*256;          // T x 512 bf16 (k / IT|FT fp32 lo)
constexpr long long OFF_V   = OFF_K   + TOK*256;          // T x 512 bf16 (CAT / v / IT|FT hi)
constexpr long long OFF_WT  = OFF_V   + TOK*256;          // transposed bf16 weights
constexpr long long WS_END  = OFF_WT  + WT_ELEMS/2 + 256; // ~250 MiB

// ----------------------------- kernels -------------------------------------

__global__ void detect_kernel(const void* mlng, int* flag){
  if (threadIdx.x == 0){
    u32 u = *(const u32*)mlng;
    *flag = (u == 0x3F803F80u) ? 1 : 0;
  }
}

struct InPtrs { const void* p[IN_N]; };

__global__ __launch_bounds__(256) void convert_kernel(InPtrs ptrs, float* __restrict__ cv,
                                                      const int* __restrict__ flag){
  long long gid = (long long)blockIdx.x * 256 + threadIdx.x;
  if (gid >= CV_TOTAL) return;
  int seg = 0;
#pragma unroll
  for (int i = 1; i < IN_N; i++) seg += (gid >= CVOFF.off[i]) ? 1 : 0;
  long long local = gid - CVOFF.off[seg];
  float v;
  if (*flag) v = b2f(((const u16*)ptrs.p[seg])[local]);
  else       v = ((const float*)ptrs.p[seg])[local];
  cv[gid] = v;
}

// W[K][N] (fp32 or bf16 input) -> WT[N][K] bf16; 32x32 LDS tiles.
__global__ __launch_bounds__(256) void wtrans_kernel(InPtrs ptrs, u16* __restrict__ WTb,
                                                     const int* __restrict__ flag){
  int wz = blockIdx.z;
  int K = WTB_K[wz], N = WTB_N[wz];
  int n0 = blockIdx.x * 32, k0 = blockIdx.y * 32;
  if (n0 >= N || k0 >= K) return;
  const void* W = ptrs.p[WTB_IN[wz]];
  u16* WT = WTb + WTO[wz];
  __shared__ u16 tile[32][34];
  int tx = threadIdx.x & 31, ty = threadIdx.x >> 5;
  bool bf = (*flag != 0);
#pragma unroll
  for (int i = 0; i < 4; i++){
    size_t src = (size_t)(k0 + ty + i*8)*N + n0 + tx;
    tile[ty + i*8][tx] = bf ? ((const u16*)W)[src] : f2b(((const float*)W)[src]);
  }
  __syncthreads();
#pragma unroll
  for (int i = 0; i < 4; i++)
    WT[(size_t)(n0 + ty + i*8)*K + k0 + tx] = tile[tx][ty + i*8];
}

__global__ __launch_bounds__(256) void cat_kernel(const float* __restrict__ xs,
    const int* __restrict__ xe, const int* __restrict__ xp,
    const float* __restrict__ ee, const float* __restrict__ ep,
    float* __restrict__ CAT){
  int gid = blockIdx.x * 256 + threadIdx.x;   // T*40
  int c = gid % 40; int t = gid / 40; int b = t >> 8;
  float v;
  if (c < 32)      v = xs[(size_t)t*32 + c];
  else if (c < 36) v = ee[xe[b]*4 + (c - 32)];
  else             v = ep[xp[b]*4 + (c - 36)];
  CAT[(size_t)t*40 + c] = v;
}

// SIMT GEMM kept for W_in (K=40, fp32 in/out)
template<typename TA, typename TC>
__global__ __launch_bounds__(256) void gemm_kernel(
    const TA* __restrict__ A, int lda,
    const float* __restrict__ Wm, const float* __restrict__ bias,
    TC* __restrict__ Cc, int ldc, const float* __restrict__ resid,
    int M, int N, int K)
{
  __shared__ float As[16][68];
  __shared__ float Bs[16][68];
  const int bm = blockIdx.y * 64, bn = blockIdx.x * 64;
  const int tid = threadIdx.x, tx = tid & 15, ty = tid >> 4;
  float acc[4][4] = {};
  for (int k0 = 0; k0 < K; k0 += 16){
#pragma unroll
    for (int i = 0; i < 4; i++){
      int idx = tid + i*256;
      int m = idx >> 4, kq = idx & 15;
      As[kq][m] = (k0 + kq < K) ? ldval(A[(size_t)(bm + m)*lda + k0 + kq]) : 0.f;
      int kk = idx >> 6, n = idx & 63;
      Bs[kk][n] = (k0 + kk < K) ? Wm[(size_t)(k0 + kk)*N + bn + n] : 0.f;
    }
    __syncthreads();
#pragma unroll
    for (int kq = 0; kq < 16; kq++){
      float av[4], bv[4];
#pragma unroll
      for (int i = 0; i < 4; i++) av[i] = As[kq][ty*4 + i];
#pragma unroll
      for (int j = 0; j < 4; j++) bv[j] = Bs[kq][tx*4 + j];
#pragma unroll
      for (int i = 0; i < 4; i++)
#pragma unroll
        for (int j = 0; j < 4; j++) acc[i][j] += av[i]*bv[j];
    }
    __syncthreads();
  }
#pragma unroll
  for (int i = 0; i < 4; i++){
    int m = bm + ty*4 + i;
#pragma unroll
    for (int j = 0; j < 4; j++){
      int n = bn + tx*4 + j;
      float v = acc[i][j] + bias[n];
      if (resid) v += resid[(size_t)m*ldc + n];
      stval(&Cc[(size_t)m*ldc + n], v);
    }
  }
}

// MFMA GEMM: 128x128 macro tile, 4 waves 2x2, each 64x64 via 4x4 mfma_16x16x32.
template<typename TC>
__global__ __launch_bounds__(256) void gemm_mfma(
    const u16* __restrict__ A, int lda,
    const u16* __restrict__ WT,
    const float* __restrict__ bias,
    TC* __restrict__ Cc, int ldc, const float* __restrict__ resid,
    int N, int K)
{
  __shared__ alignas(16) u16 As[128*40];
  __shared__ alignas(16) u16 Bs[128*40];
  const int bm = blockIdx.y * 128, bn = blockIdx.x * 128;
  const int tid = threadIdx.x;
  const int w = tid >> 6, lane = tid & 63, lm = lane & 15, q = lane >> 4;
  const int wm = w >> 1, wn = w & 1;
  float4v acc[4][4] = {};
  for (int k0 = 0; k0 < K; k0 += 32){
    __syncthreads();
#pragma unroll
    for (int c = tid; c < 512; c += 256){
      int r = c >> 2, ch = c & 3;
      *(uint4*)&As[r*40 + ch*8] = *(const uint4*)&A[(size_t)(bm + r)*lda + k0 + ch*8];
      int n = bn + r;
      uint4 bv = {0u,0u,0u,0u};
      if (n < N) bv = *(const uint4*)&WT[(size_t)n*K + k0 + ch*8];
      *(uint4*)&Bs[r*40 + ch*8] = bv;
    }
    __syncthreads();
    short8 a[4], b[4];
#pragma unroll
    for (int i = 0; i < 4; i++)
      a[i] = *(const short8*)&As[(wm*64 + i*16 + lm)*40 + q*8];
#pragma unroll
    for (int j = 0; j < 4; j++)
      b[j] = *(const short8*)&Bs[(wn*64 + j*16 + lm)*40 + q*8];
#pragma unroll
    for (int i = 0; i < 4; i++)
#pragma unroll
      for (int j = 0; j < 4; j++)
        acc[i][j] = __builtin_amdgcn_mfma_f32_16x16x32_bf16(a[i], b[j], acc[i][j], 0, 0, 0);
  }
#pragma unroll
  for (int i = 0; i < 4; i++){
#pragma unroll
    for (int j = 0; j < 4; j++){
      int col = bn + wn*64 + j*16 + lm;
      if (col < N){
#pragma unroll
        for (int r = 0; r < 4; r++){
          int row = bm + wm*64 + i*16 + q*4 + r;
          float v = acc[i][j][r] + bias[col];
          if (resid) v += resid[(size_t)row*ldc + col];
          stval(&Cc[(size_t)row*ldc + col], v);
        }
      }
    }
  }
}

// LayerNorm: one wave per row, float4 loads, shuffle-only reductions.
__global__ __launch_bounds__(256) void ln_kernel(const float* __restrict__ Xin,
    const float* __restrict__ g, const float* __restrict__ b,
    u16* __restrict__ out, float eps){
  int t = blockIdx.x*4 + (threadIdx.x >> 6);
  int e = threadIdx.x & 63;
  float4 v = *(const float4*)&Xin[(size_t)t*256 + e*4];
  float su = v.x + v.y + v.z + v.w;
#pragma unroll
  for (int o = 32; o > 0; o >>= 1) su += __shfl_xor(su, o, 64);
  float mu = su * (1.f/256.f);
  float d0 = v.x - mu, d1 = v.y - mu, d2 = v.z - mu, d3 = v.w - mu;
  float sq = d0*d0 + d1*d1 + d2*d2 + d3*d3;
#pragma unroll
  for (int o = 32; o > 0; o >>= 1) sq += __shfl_xor(sq, o, 64);
  float rstd = rsqrtf(sq * (1.f/256.f) + eps);
  float4 gv = *(const float4*)&g[e*4];
  float4 bv = *(const float4*)&b[e*4];
  ushort4 o4;
  o4.x = f2b(d0*rstd*gv.x + bv.x);
  o4.y = f2b(d1*rstd*gv.y + bv.y);
  o4.z = f2b(d2*rstd*gv.z + bv.z);
  o4.w = f2b(d3*rstd*gv.w + bv.w);
  *(ushort4*)&out[(size_t)t*256 + e*4] = o4;
}

// depthwise causal conv (K=4) + silu, ushort8 vectorized (8 channels/thread)
__global__ __launch_bounds__(256) void conv_silu_kernel(const u16* __restrict__ Xc, int ldx, int C,
    const float* __restrict__ w, const float* __restrict__ bias, u16* __restrict__ Y){
  int nc = C >> 3;
  long long gid = (long long)blockIdx.x * 256 + threadIdx.x;   // T*nc
  int c8 = (int)(gid % nc) * 8; long long t = gid / nc;
  int s = (int)(t & 255);
  float acc[8];
#pragma unroll
  for (int i = 0; i < 8; i++) acc[i] = bias[c8 + i];
#pragma unroll
  for (int j = 0; j < 4; j++){
    int so = s - 3 + j;
    if (so >= 0){
      ushort8v xv = *(const ushort8v*)&Xc[(size_t)(t - 3 + j)*ldx + c8];
#pragma unroll
      for (int i = 0; i < 8; i++) acc[i] += b2f(xv[i]) * w[j*C + c8 + i];
    }
  }
  ushort8v o8;
#pragma unroll
  for (int i = 0; i < 8; i++) o8[i] = f2b(acc[i] / (1.f + __expf(-acc[i])));
  *(ushort8v*)&Y[(size_t)t*C + c8] = o8;
}

// ipre/fpre: gin=[q|k|v] (T x 1536) @ Wi/Wf (1536 x 4), ushort8 inner loads
__global__ __launch_bounds__(256) void gates_kernel(
    const u16* __restrict__ Q, const u16* __restrict__ Kb, const u16* __restrict__ V,
    const float* __restrict__ Wi, const float* __restrict__ bi,
    const float* __restrict__ Wf, const float* __restrict__ bf,
    float* __restrict__ IP, float* __restrict__ FP){
  int t = blockIdx.x; int tid = threadIdx.x;
  int o = tid & 7, seg = tid >> 3;
  int b = t >> 8, s = t & 255;
  int g = o & 3;
  const float* Wg = (o >= 4) ? Wf : Wi;
  float part = 0.f;
#pragma unroll
  for (int i = 0; i < 6; i++){
    int k8 = seg*48 + i*8;
    const u16* src; int off;
    if (k8 < 512){ src = Q; off = k8; }
    else if (k8 < 1024){ src = Kb; off = k8 - 512; }
    else { src = V; off = k8 - 1024; }
    ushort8v gv = *(const ushort8v*)&src[(size_t)t*512 + off];
#pragma unroll
    for (int j = 0; j < 8; j++) part += b2f(gv[j]) * Wg[(k8 + j)*4 + g];
  }
  __shared__ float red[256];
  red[tid] = part; __syncthreads();
  if (tid < 8){
    float tot = 0.f;
    for (int ss = 0; ss < 32; ss++) tot += red[ss*8 + tid];
    int gg = tid & 3;
    if (tid < 4) IP[(b*4 + gg)*256 + s] = tot + bi[gg];
    else         FP[(b*4 + gg)*256 + s] = tot + bf[gg];
  }
}

// per (b,h): F=cumsum(logsigmoid(fpre)); G=ipre-F; M=cummax(G)
__global__ __launch_bounds__(256) void fscan_kernel(const float* __restrict__ IP,
    const float* __restrict__ FP, float* __restrict__ Fo, float* __restrict__ Go,
    float* __restrict__ Mo){
  int bh = blockIdx.x; int s = threadIdx.x;
  int idx = bh*256 + s;
  __shared__ float buf[256];
  float fp = FP[idx];
  float lfg = fminf(fp, 0.f) - log1pf(expf(-fabsf(fp)));
  float v = lfg;
  buf[s] = v; __syncthreads();
  for (int off = 1; off < 256; off <<= 1){
    float tv = (s >= off) ? buf[s - off] : 0.f;
    __syncthreads();
    v += tv; buf[s] = v;
    __syncthreads();
  }
  float Fv = v;
  float g = IP[idx] - Fv;
  float mv = g;
  buf[s] = mv; __syncthreads();
  for (int off = 1; off < 256; off <<= 1){
    float tv = (s >= off) ? buf[s - off] : -3.0e38f;
    __syncthreads();
    mv = fmaxf(mv, tv); buf[s] = mv;
    __syncthreads();
  }
  Fo[idx] = Fv; Go[idx] = g; Mo[idx] = mv;
}

// Fused MFMA mLSTM attention (unchanged).
__global__ __launch_bounds__(256) void attn_kernel(
    const u16* __restrict__ Q, const u16* __restrict__ Kb, const u16* __restrict__ V,
    const float* __restrict__ G, const float* __restrict__ Mx, const float* __restrict__ F,
    const u16* __restrict__ Ab, const u16* __restrict__ UPb,
    const float* __restrict__ ng, const float* __restrict__ nb,
    const float* __restrict__ skip, u16* __restrict__ Yb)
{
  int bh = blockIdx.y, b = bh >> 2, h = bh & 3;
  int tt = blockIdx.x, t0 = tt * 64;
  int tid = threadIdx.x;
  int w = tid >> 6, lane = tid & 63, lm = lane & 15, q = lane >> 4;
  int gbase = bh * 256;

  __shared__ alignas(16) u16 Qs[64*136];
  __shared__ alignas(16) u16 Ks[64*136];
  __shared__ alignas(16) u16 Vt[128*72];
  __shared__ alignas(16) u16 Ps[64*72];
  __shared__ float rs[64];

#pragma unroll
  for (int c = tid; c < 1024; c += 256){
    int r = c >> 4, ch = c & 15;
    *(uint4*)&Qs[r*136 + ch*8] =
      *(const uint4*)&Q[((size_t)(b*256 + t0 + r))*512 + h*128 + ch*8];
  }
  if (tid < 64) rs[tid] = 0.f;

  float mrow[4];
#pragma unroll
  for (int r = 0; r < 4; r++) mrow[r] = Mx[gbase + t0 + w*16 + q*4 + r];

  float4v acc2[8] = {};
  const float scale = 0.08838834764831845f;

  for (int ss = 0; ss <= tt; ss++){
    int s0 = ss * 64;
    __syncthreads();
#pragma unroll
    for (int c = tid; c < 1024; c += 256){
      int r = c >> 4, ch = c & 15;
      *(uint4*)&Ks[r*136 + ch*8] =
        *(const uint4*)&Kb[((size_t)(b*256 + s0 + r))*512 + h*128 + ch*8];
    }
#pragma unroll
    for (int c = tid; c < 1024; c += 256){
      int sl = c & 63, db = c >> 6;
      ushort8v v = *(const ushort8v*)&V[((size_t)(b*256 + s0 + sl))*512 + h*128 + db*8];
#pragma unroll
      for (int j = 0; j < 8; j++) Vt[(db*8 + j)*72 + sl] = v[j];
    }
    __syncthreads();
    float4v sacc[4] = {};
#pragma unroll
    for (int k0 = 0; k0 < 128; k0 += 32){
      short8 a = *(const short8*)&Qs[(w*16 + lm)*136 + k0 + q*8];
#pragma unroll
      for (int j = 0; j < 4; j++){
        short8 bb = *(const short8*)&Ks[(j*16 + lm)*136 + k0 + q*8];
        sacc[j] = __builtin_amdgcn_mfma_f32_16x16x32_bf16(a, bb, sacc[j], 0, 0, 0);
      }
    }
    float rp[4] = {0.f, 0.f, 0.f, 0.f};
#pragma unroll
    for (int j = 0; j < 4; j++){
      int scol = s0 + j*16 + lm;
      float gq = G[gbase + scol];
#pragma unroll
      for (int r = 0; r < 4; r++){
        int trow = t0 + w*16 + q*4 + r;
        float cval = (scol <= trow) ? sacc[j][r]*scale*__expf(gq - mrow[r]) : 0.f;
        Ps[(w*16 + q*4 + r)*72 + j*16 + lm] = f2b(cval);
        rp[r] += cval;
      }
    }
#pragma unroll
    for (int r = 0; r < 4; r++){
#pragma unroll
      for (int m = 1; m < 16; m <<= 1) rp[r] += __shfl_xor(rp[r], m, 16);
      if (lm == 0) rs[w*16 + q*4 + r] += rp[r];
    }
#pragma unroll
    for (int k0 = 0; k0 < 64; k0 += 32){
      short8 a = *(const short8*)&Ps[(w*16 + lm)*72 + k0 + q*8];
#pragma unroll
      for (int jd = 0; jd < 8; jd++){
        short8 bb = *(const short8*)&Vt[(jd*16 + lm)*72 + k0 + q*8];
        acc2[jd] = __builtin_amdgcn_mfma_f32_16x16x32_bf16(a, bb, acc2[jd], 0, 0, 0);
      }
    }
  }
  __syncthreads();
#pragma unroll
  for (int r = 0; r < 4; r++){
    int rl = w*16 + q*4 + r;
    int t = t0 + rl;
    float Fv = F[gbase + t];
    float nrm = fmaxf(fabsf(rs[rl]), __expf(-(Fv + mrow[r])));
    float inv = 1.f / nrm;
    float vv[8];
    float su = 0.f;
#pragma unroll
    for (int jd = 0; jd < 8; jd++){ vv[jd] = acc2[jd][r]*inv; su += vv[jd]; }
#pragma unroll
    for (int m = 1; m < 16; m <<= 1) su += __shfl_xor(su, m, 16);
    float mu = su * (1.f/128.f);
    float sq = 0.f;
#pragma unroll
    for (int jd = 0; jd < 8; jd++){ vv[jd] -= mu; sq += vv[jd]*vv[jd]; }
#pragma unroll
    for (int m = 1; m < 16; m <<= 1) sq += __shfl_xor(sq, m, 16);
    float rstd = rsqrtf(sq * (1.f/128.f) + 1e-6f);
#pragma unroll
    for (int jd = 0; jd < 8; jd++){
      int c = h*128 + jd*16 + lm;
      float hv = vv[jd]*rstd*ng[c] + nb[c];
      float av = b2f(Ab[(size_t)t*512 + c]);
      float zg = b2f(UPb[(size_t)t*1024 + 512 + c]);
      float sz = zg / (1.f + __expf(-zg));
      Yb[(size_t)t*512 + c] = f2b((hv + skip[c]*av)*sz);
    }
  }
}

// sLSTM recurrence: 5 waves per (b,h), per-step streaming, RAW barriers.
// Gate inputs are two combined [T x 512] fp32 buffers: G1 = [IT|FT],
// G2 = [ZT|OT]; wave w streams its own column block 2 steps ahead (loads
// stay in flight across raw s_barrier -- no vmcnt drain).
//  - waves 0..3: matvec over 16 d's each -> float4 partial -> LDS;
//    lds_barrier(); replicated 4-way reduce + scalar tail (bitwise identical)
//    keeps (h,c,n,m) in all 4 waves; wave 1 publishes h to 2-slot hbuf ring.
//  - wave 4: one step behind; DPP headnorm + Xr read-add-write.
//  - 257 barriers on both divergent paths.
__global__ __launch_bounds__(320) void scan_kernel(
    const float* __restrict__ G1, const float* __restrict__ G2,
    const float* __restrict__ Ri, const float* __restrict__ Rf,
    const float* __restrict__ Rz, const float* __restrict__ Ro,
    const float* __restrict__ sng, const float* __restrict__ snb,
    float* __restrict__ Xr){
  int bh = blockIdx.x; int b = bh >> 2, h = bh & 3;
  int e = threadIdx.x & 63;
  int w = threadIdx.x >> 6;                 // 0..4, wave-uniform
  __shared__ float4 part[2][4][64];         // [s&1][wave][e] = 4 gate partials
  __shared__ float hbuf[2][64];             // [s&1][e] = h(s)
  size_t xrow = ((size_t)b*256)*256 + h*64 + e;   // Xr stride 256

  if (w < 4){
    // R fragments: rX[k] = R_X[h][w*16+k][e]
    float r0[16], r1[16], r2[16], r3[16];
    const float* Rp0 = Ri + h*4096 + w*1024;
    const float* Rp1 = Rf + h*4096 + w*1024;
    const float* Rp2 = Rz + h*4096 + w*1024;
    const float* Rp3 = Ro + h*4096 + w*1024;
#pragma unroll
    for (int d = 0; d < 16; d++){
      r0[d] = Rp0[d*64 + e];
      r1[d] = Rp1[d*64 + e];
      r2[d] = Rp2[d*64 + e];
      r3[d] = Rp3[d*64 + e];
    }
    // this wave's gate stream: stride 512, col block (w&1)*256
    const float* Gp = (w < 2) ? G1 : G2;
    size_t grow = ((size_t)b*256)*512 + ((w & 1) ? 256 : 0) + h*64 + e;
    float hS = 0.f, cS = 0.f, nS = 0.f, mS = 0.f;
    float gv = Gp[grow];                       // s = 0
    float gn = Gp[grow + 512];                 // s = 1
    for (int s = 0; s < 256; s++){
      float gn2 = 0.f;
      if (s < 254) gn2 = Gp[grow + (size_t)(s + 2)*512];
      // phase A: partial matvec over this wave's 16 d's (8 chains)
      float ai0 = 0.f, ai1 = 0.f, af0 = 0.f, af1 = 0.f;
      float az0 = 0.f, az1 = 0.f, ao0 = 0.f, ao1 = 0.f;
#pragma unroll
      for (int k = 0; k < 16; k += 2){
        float h0 = __builtin_bit_cast(float,
            __builtin_amdgcn_readlane(__builtin_bit_cast(int, hS), w*16 + k));
        float h1 = __builtin_bit_cast(float,
            __builtin_amdgcn_readlane(__builtin_bit_cast(int, hS), w*16 + k + 1));
        ai0 += h0*r0[k]; ai1 += h1*r0[k+1];
        af0 += h0*r1[k]; af1 += h1*r1[k+1];
        az0 += h0*r2[k]; az1 += h1*r2[k+1];
        ao0 += h0*r3[k]; ao1 += h1*r3[k+1];
      }
      float4 p;
      p.x = ai0 + ai1; p.y = af0 + af1; p.z = az0 + az1; p.w = ao0 + ao1;
      if      (w == 0) p.x += gv;
      else if (w == 1) p.y += gv;
      else if (w == 2) p.z += gv;
      else             p.w += gv;
      part[s & 1][w][e] = p;
      lds_barrier();
      // phase B: replicated reduce + scalar tail (bitwise identical, 4 waves)
      float4 q0 = part[s & 1][0][e];
      float4 q1 = part[s & 1][1][e];
      float4 q2 = part[s & 1][2][e];
      float4 q3 = part[s & 1][3][e];
      float ip = (q0.x + q1.x) + (q2.x + q3.x);
      float fp = (q0.y + q1.y) + (q2.y + q3.y);
      float zr = (q0.z + q1.z) + (q2.z + q3.z);
      float og = (q0.w + q1.w) + (q2.w + q3.w);
      float zp = 1.f - 2.f*__builtin_amdgcn_rcpf(__expf(2.f*zr) + 1.f);
      float op = __builtin_amdgcn_rcpf(1.f + __expf(-og));
      float mn = fmaxf(fp + mS, ip);
      float ig = __expf(ip - mn);
      float fg = __expf(fp + mS - mn);
      cS = fg*cS + ig*zp;
      nS = fg*nS + ig;
      mS = mn;
      hS = op * cS * __builtin_amdgcn_rcpf(nS);
      if (w == 1) hbuf[s & 1][e] = hS;
      gv = gn; gn = gn2;
    }
    lds_barrier();  // pairs with wave 4's epilogue barrier
  } else {
    // output wave: one step behind; DPP headnorm; per-step Xr stream
    float gw = sng[h*64 + e], bw = snb[h*64 + e];
    float xp = 0.f, xc = 0.f;
    for (int s = 0; s < 256; s++){
      xc = Xr[xrow + (size_t)s*256];   // stays in flight across the barrier
      lds_barrier();
      if (s > 0){
        float hv = hbuf[(s - 1) & 1][e];
        float su, sq;
        dpp_sum2(hv, hv*hv, su, sq);
        float mu = su * (1.f/64.f);
        float var = fmaxf(sq * (1.f/64.f) - mu*mu, 0.f);
        float nv = (hv - mu) * rsqrtf(var + 1e-6f) * gw + bw;
        Xr[xrow + (size_t)(s - 1)*256] = xp + nv;
      }
      xp = xc;
    }
    lds_barrier();
    // epilogue: row 255 (h(255) in slot 255&1 == 1)
    float hv = hbuf[1][e];
    float su, sq;
    dpp_sum2(hv, hv*hv, su, sq);
    float mu = su * (1.f/64.f);
    float var = fmaxf(sq * (1.f/64.f) - mu*mu, 0.f);
    float nv = (hv - mu) * rsqrtf(var + 1e-6f) * gw + bw;
    Xr[xrow + (size_t)255*256] = xp + nv;
  }
}

// FFN activation: P = gelu_tanh(g) * u, ushort8 vectorized
__global__ __launch_bounds__(256) void ffn_act_kernel(const u16* __restrict__ GU,
                                                      u16* __restrict__ P){
  long long gid = (long long)blockIdx.x * 256 + threadIdx.x;   // T*44
  int j8 = (int)(gid % 44) * 8; long long t = gid / 44;
  ushort8v gv = *(const ushort8v*)&GU[(size_t)t*704 + j8];
  ushort8v uv = *(const ushort8v*)&GU[(size_t)t*704 + 352 + j8];
  ushort8v o8;
#pragma unroll
  for (int i = 0; i < 8; i++){
    float g = b2f(gv[i]);
    float u = b2f(uv[i]);
    float inner = 0.7978845608028654f * (g + 0.044715f*g*g*g);
    float gel = 0.5f * g * (1.f + tanhf(inner));
    o8[i] = f2b(gel * u);
  }
  *(ushort8v*)&P[(size_t)t*352 + j8] = o8;
}

// output head: relu(last@W1+b1)@W2+b2, write in detected dtype
__global__ __launch_bounds__(64) void head_kernel(const float* __restrict__ X,
    const float* __restrict__ W1, const float* __restrict__ b1,
    const float* __restrict__ W2, const float* __restrict__ b2,
    void* out, const int* __restrict__ flag){
  int b = blockIdx.x, j = threadIdx.x;
  __shared__ float L[256];
  __shared__ float H1[64];
  for (int i = j; i < 256; i += 64) L[i] = X[((size_t)(b*256 + 255))*256 + i];
  __syncthreads();
  float acc = b1[j];
  for (int d = 0; d < 256; d++) acc += L[d] * W1[d*64 + j];
  H1[j] = fmaxf(acc, 0.f);
  __syncthreads();
  if (j < 3){
    float o = b2[j];
    for (int k2 = 0; k2 < 64; k2++) o += H1[k2] * W2[k2*3 + j];
    if (*flag) ((u16*)out)[b*3 + j] = f2b(o);
    else       ((float*)out)[b*3 + j] = o;
  }
}

// ----------------------------- launch --------------------------------------
extern "C" void kernel_launch(void* const* d_in, const int* in_sizes, int n_in,
                              void* d_out, int out_size, void* d_ws, size_t ws_size,
                              hipStream_t stream)
{
  if (n_in != IN_N) return;
  for (int i = 0; i < IN_N; i++) if ((long long)in_sizes[i] != IN_SIZES[i]) return;
  if (ws_size < (size_t)WS_END * 4) return;
  if (out_size != 384) return;

  float* ws = (float*)d_ws;
  float* cv = ws;
  auto cvp = [&](int i){ return cv + CVOFF.off[i]; };

  int*   flag = (int*)(ws + OFF_FLAG);
  float* IP   = ws + OFF_IP;
  float* FP   = ws + OFF_FP;
  float* Fb   = ws + OFF_F;
  float* Gb   = ws + OFF_G;
  float* Mb   = ws + OFF_M;
  float* X    = ws + OFF_X;
  u16*   XNb  = (u16*)(ws + OFF_XN);
  u16*   UPb  = (u16*)(ws + OFF_UP);
  u16*   Ab   = (u16*)(ws + OFF_A);
  u16*   Qb   = (u16*)(ws + OFF_Q);
  u16*   Kbb  = (u16*)(ws + OFF_K);
  u16*   Vb   = (u16*)(ws + OFF_V);
  u16*   WTb  = (u16*)(ws + OFF_WT);
  // overlays (lifetimes disjoint):
  float* CAT = ws + OFF_V;
  u16*   Yb  = Qb;
  u16*   ACb = Ab;
  float* G1f = ws + OFF_K;    // [T x 512] fp32: IT|FT (spans OFF_K + OFF_V)
  float* G2f = ws + OFF_UP;   // [T x 512] fp32: ZT|OT (spans OFF_UP)
  u16*   GUb = UPb;
  u16*   Pb  = Ab;

  auto wt = [&](int widx){ return WTb + WTO[widx]; };

  InPtrs ptrs;
  for (int i = 0; i < IN_N; i++) ptrs.p[i] = d_in[i];

  const int M = 32768;
  detect_kernel<<<1, 64, 0, stream>>>(d_in[7], flag);
  int cvblocks = (int)((CV_TOTAL + 255) / 256);
  convert_kernel<<<cvblocks, 256, 0, stream>>>(ptrs, cv, flag);
  wtrans_kernel<<<dim3(32, 16, 11), 256, 0, stream>>>(ptrs, WTb, flag);
  cat_kernel<<<5120, 256, 0, stream>>>(cvp(0), (const int*)d_in[1], (const int*)d_in[2],
                                       cvp(3), cvp(4), CAT);
  gemm_kernel<float, float><<<dim3(4, 512), 256, 0, stream>>>(CAT, 40, cvp(5), cvp(6),
      X, 256, nullptr, M, 256, 40);
  // ---- mLSTM block ----
  ln_kernel<<<8192, 256, 0, stream>>>(X, cvp(7), cvp(8), XNb, 1e-5f);
  gemm_mfma<u16><<<dim3(8, 256), 256, 0, stream>>>(XNb, 256, wt(0), cvp(10),
      UPb, 1024, nullptr, 1024, 256);
  conv_silu_kernel<<<8192, 256, 0, stream>>>(UPb, 1024, 512, cvp(11), cvp(12), Ab);
  gemm_mfma<u16><<<dim3(4, 256), 256, 0, stream>>>(Ab, 512, wt(1), cvp(14),
      Qb, 512, nullptr, 512, 512);
  gemm_mfma<u16><<<dim3(4, 256), 256, 0, stream>>>(Ab, 512, wt(2), cvp(16),
      Kbb, 512, nullptr, 512, 512);
  gemm_mfma<u16><<<dim3(4, 256), 256, 0, stream>>>(UPb, 1024, wt(3), cvp(18),
      Vb, 512, nullptr, 512, 512);
  gates_kernel<<<M, 256, 0, stream>>>(Qb, Kbb, Vb, cvp(19), cvp(20), cvp(21), cvp(22), IP, FP);
  fscan_kernel<<<512, 256, 0, stream>>>(IP, FP, Fb, Gb, Mb);
  attn_kernel<<<dim3(4, 512), 256, 0, stream>>>(Qb, Kbb, Vb, Gb, Mb, Fb,
      Ab, UPb, cvp(24), cvp(25), cvp(23), Yb);
  gemm_mfma<float><<<dim3(2, 256), 256, 0, stream>>>(Yb, 512, wt(4), cvp(27),
      X, 256, X, 256, 512);
  // ---- sLSTM block ----
  ln_kernel<<<8192, 256, 0, stream>>>(X, cvp(28), cvp(29), XNb, 1e-5f);
  conv_silu_kernel<<<4096, 256, 0, stream>>>(XNb, 256, 256, cvp(30), cvp(31), ACb);
  // merged gate GEMMs: [AC]@[s_Wi|s_Wf] -> G1 (IT|FT), [XN]@[s_Wz|s_Wo] -> G2
  gemm_mfma<float><<<dim3(4, 256), 256, 0, stream>>>(ACb, 256, wt(5), cvp(33),
      G1f, 512, nullptr, 512, 256);
  gemm_mfma<float><<<dim3(4, 256), 256, 0, stream>>>(XNb, 256, wt(7), cvp(37),
      G2f, 512, nullptr, 512, 256);
  scan_kernel<<<512, 320, 0, stream>>>(G1f, G2f, cvp(40), cvp(41), cvp(42), cvp(43),
      cvp(44), cvp(45), X);
  // ---- FFN ----
  ln_kernel<<<8192, 256, 0, stream>>>(X, cvp(46), cvp(47), XNb, 1e-5f);
  gemm_mfma<u16><<<dim3(6, 256), 256, 0, stream>>>(XNb, 256, wt(9), cvp(49),
      GUb, 704, nullptr, 704, 256);
  ffn_act_kernel<<<5632, 256, 0, stream>>>(GUb, Pb);
  gemm_mfma<float><<<dim3(2, 256), 256, 0, stream>>>(Pb, 352, wt(10), cvp(51),
      X, 256, X, 256, 352);
  // ---- head ----
  head_kernel<<<128, 64, 0, stream>>>(X, cvp(52), cvp(53), cvp(54), cvp(55), d_out, flag);
}

// Round 6
// 1062.993 us; speedup vs baseline: 1.0937x; 1.0837x over previous
//
#include <hip/hip_runtime.h>
#include <cstdint>
#include <cstddef>

// ---------------------------------------------------------------------------
// Model_xLSTM: B=128 S=256 NF=32 E=4 D=256 H=4 DI=512 DHM=128 DHS=64 K=4 FF=352
// Round 11 (post-mortem R10: raw s_barrier + sched_barrier(0) fences REGRESSED
// scan 194->221 us -- the fences blocked compiler ILP across phase boundaries,
// which is what actually hides the scan's dependent-latency chain. Merged gate
// GEMMs were good.):
//  * scan: R10 data layout kept (G1=[IT|FT], G2=[ZT|OT] stride-512 streams,
//    per-wave single-gate load, DPP headnorm on wave 4) but ALL barriers back
//    to __syncthreads() -- isolates barrier type as the variable.
//  * gemm_mfma: double-buffered 2-phase pipeline (T3-minimum recipe): stage
//    tile0; loop { issue next-tile loads to regs; ds_read+MFMA cur; ds_write
//    cur^1; ONE barrier }. Halves barriers, hides load latency under MFMA.
//    LDS 20KB -> 40KB (still 4 blocks/CU).
// Rest frozen (R4/R5 + R10 merged gate GEMMs).
// ---------------------------------------------------------------------------

using u16 = unsigned short;
using u32 = unsigned int;

typedef __attribute__((ext_vector_type(8))) short short8;
typedef __attribute__((ext_vector_type(8))) unsigned short ushort8v;
typedef __attribute__((ext_vector_type(4))) float float4v;

#define DEVINL __device__ __forceinline__

DEVINL float b2f(u16 u){ u32 x = ((u32)u) << 16; return __builtin_bit_cast(float, x); }
DEVINL u16 f2b(float f){
  u32 x = __builtin_bit_cast(u32, f);
  u32 r = x + 0x7FFFu + ((x >> 16) & 1u);   // RTNE
  return (u16)(r >> 16);
}
DEVINL float ldval(float x){ return x; }
DEVINL float ldval(u16 x){ return b2f(x); }
DEVINL void stval(float* p, float v){ *p = v; }
DEVINL void stval(u16* p, float v){ *p = f2b(v); }

// dual-chain 64-lane sum via DPP (gfx9 row ops), results broadcast via lane 63
DEVINL void dpp_sum2(float a, float b, float& oa, float& ob){
  int xa, xb;
  xa = __builtin_amdgcn_update_dpp(0, __builtin_bit_cast(int, a), 0x111, 0xf, 0xf, true);
  xb = __builtin_amdgcn_update_dpp(0, __builtin_bit_cast(int, b), 0x111, 0xf, 0xf, true);
  a += __builtin_bit_cast(float, xa); b += __builtin_bit_cast(float, xb);
  xa = __builtin_amdgcn_update_dpp(0, __builtin_bit_cast(int, a), 0x112, 0xf, 0xf, true);
  xb = __builtin_amdgcn_update_dpp(0, __builtin_bit_cast(int, b), 0x112, 0xf, 0xf, true);
  a += __builtin_bit_cast(float, xa); b += __builtin_bit_cast(float, xb);
  xa = __builtin_amdgcn_update_dpp(0, __builtin_bit_cast(int, a), 0x114, 0xf, 0xf, true);
  xb = __builtin_amdgcn_update_dpp(0, __builtin_bit_cast(int, b), 0x114, 0xf, 0xf, true);
  a += __builtin_bit_cast(float, xa); b += __builtin_bit_cast(float, xb);
  xa = __builtin_amdgcn_update_dpp(0, __builtin_bit_cast(int, a), 0x118, 0xf, 0xf, true);
  xb = __builtin_amdgcn_update_dpp(0, __builtin_bit_cast(int, b), 0x118, 0xf, 0xf, true);
  a += __builtin_bit_cast(float, xa); b += __builtin_bit_cast(float, xb);
  xa = __builtin_amdgcn_update_dpp(0, __builtin_bit_cast(int, a), 0x142, 0xf, 0xf, true);
  xb = __builtin_amdgcn_update_dpp(0, __builtin_bit_cast(int, b), 0x142, 0xf, 0xf, true);
  a += __builtin_bit_cast(float, xa); b += __builtin_bit_cast(float, xb);
  xa = __builtin_amdgcn_update_dpp(0, __builtin_bit_cast(int, a), 0x143, 0xf, 0xf, true);
  xb = __builtin_amdgcn_update_dpp(0, __builtin_bit_cast(int, b), 0x143, 0xf, 0xf, true);
  a += __builtin_bit_cast(float, xa); b += __builtin_bit_cast(float, xb);
  oa = __builtin_bit_cast(float, __builtin_amdgcn_readlane(__builtin_bit_cast(int, a), 63));
  ob = __builtin_bit_cast(float, __builtin_amdgcn_readlane(__builtin_bit_cast(int, b), 63));
}

// ----------------------------- input table ---------------------------------
constexpr int IN_N = 56;
constexpr long long IN_SIZES[IN_N] = {
  1048576, 128, 128, 404, 28, 10240, 256, 256, 256,
  262144, 1024, 2048, 512,
  262144, 512, 262144, 512, 262144, 512,
  6144, 4, 6144, 4,
  512, 512, 512, 131072, 256,
  256, 256, 1024, 256,
  65536, 256, 65536, 256, 65536, 256, 65536, 256,
  16384, 16384, 16384, 16384,
  256, 256,
  256, 256, 180224, 704, 90112, 256,
  16384, 64, 192, 3 };

constexpr bool is_wt_input(int i){
  return i==9 || i==13 || i==15 || i==17 || i==26 || i==32 || i==34 || i==36
      || i==38 || i==48 || i==50;
}

struct CvOff { long long off[IN_N+1]; };
constexpr CvOff make_off(){
  CvOff o{};
  long long a = 0;
  for (int i = 0; i < IN_N; i++){
    o.off[i] = a;
    long long s = IN_SIZES[i];
    if (i == 1 || i == 2 || is_wt_input(i)) s = 0;
    a += s;
  }
  o.off[IN_N] = a;
  return o;
}
constexpr CvOff CVOFF = make_off();
constexpr long long CV_TOTAL = CVOFF.off[IN_N];

// transposed-weight table
constexpr int WT_NW = 11;
constexpr int WTB_IN[WT_NW] = {9, 13, 15, 17, 26, 32, 34, 36, 38, 48, 50};
constexpr int WTB_K[WT_NW]  = {256,512,512,512,512,256,256,256,256,256,352};
constexpr int WTB_N[WT_NW]  = {1024,512,512,512,256,256,256,256,256,704,256};
constexpr long long WTO[WT_NW+1] = {0, 262144, 524288, 786432, 1048576, 1179648,
  1245184, 1310720, 1376256, 1441792, 1622016, 1712128};
constexpr long long WT_ELEMS = WTO[WT_NW];

// ----------------------------- ws layout (float units) ---------------------
constexpr long long alignup(long long x){ return ((x + 255) / 256) * 256; }
constexpr long long TOK = 32768;            // B*S
constexpr long long OFF_FLAG = alignup(CV_TOTAL);
constexpr long long OFF_IP  = OFF_FLAG + 64;
constexpr long long OFF_FP  = OFF_IP  + 131072;
constexpr long long OFF_F   = OFF_FP  + 131072;
constexpr long long OFF_G   = OFF_F   + 131072;
constexpr long long OFF_M   = OFF_G   + 131072;
constexpr long long OFF_X   = OFF_M   + 131072;           // T x 256 fp32
constexpr long long OFF_XN  = OFF_X   + TOK*256;          // T x 256 bf16
constexpr long long OFF_UP  = OFF_XN  + TOK*128;          // T x 1024 bf16 (xm|zg / ZT|OT fp32)
constexpr long long OFF_A   = OFF_UP  + TOK*512;          // T x 512 bf16 (a / AC / P)
constexpr long long OFF_Q   = OFF_A   + TOK*256;          // T x 512 bf16 (q / Y)
constexpr long long OFF_K   = OFF_Q   + TOK*256;          // T x 512 bf16 (k / IT|FT fp32 lo)
constexpr long long OFF_V   = OFF_K   + TOK*256;          // T x 512 bf16 (CAT / v / IT|FT hi)
constexpr long long OFF_WT  = OFF_V   + TOK*256;          // transposed bf16 weights
constexpr long long WS_END  = OFF_WT  + WT_ELEMS/2 + 256; // ~250 MiB

// ----------------------------- kernels -------------------------------------

__global__ void detect_kernel(const void* mlng, int* flag){
  if (threadIdx.x == 0){
    u32 u = *(const u32*)mlng;
    *flag = (u == 0x3F803F80u) ? 1 : 0;
  }
}

struct InPtrs { const void* p[IN_N]; };

__global__ __launch_bounds__(256) void convert_kernel(InPtrs ptrs, float* __restrict__ cv,
                                                      const int* __restrict__ flag){
  long long gid = (long long)blockIdx.x * 256 + threadIdx.x;
  if (gid >= CV_TOTAL) return;
  int seg = 0;
#pragma unroll
  for (int i = 1; i < IN_N; i++) seg += (gid >= CVOFF.off[i]) ? 1 : 0;
  long long local = gid - CVOFF.off[seg];
  float v;
  if (*flag) v = b2f(((const u16*)ptrs.p[seg])[local]);
  else       v = ((const float*)ptrs.p[seg])[local];
  cv[gid] = v;
}

// W[K][N] (fp32 or bf16 input) -> WT[N][K] bf16; 32x32 LDS tiles.
__global__ __launch_bounds__(256) void wtrans_kernel(InPtrs ptrs, u16* __restrict__ WTb,
                                                     const int* __restrict__ flag){
  int wz = blockIdx.z;
  int K = WTB_K[wz], N = WTB_N[wz];
  int n0 = blockIdx.x * 32, k0 = blockIdx.y * 32;
  if (n0 >= N || k0 >= K) return;
  const void* W = ptrs.p[WTB_IN[wz]];
  u16* WT = WTb + WTO[wz];
  __shared__ u16 tile[32][34];
  int tx = threadIdx.x & 31, ty = threadIdx.x >> 5;
  bool bf = (*flag != 0);
#pragma unroll
  for (int i = 0; i < 4; i++){
    size_t src = (size_t)(k0 + ty + i*8)*N + n0 + tx;
    tile[ty + i*8][tx] = bf ? ((const u16*)W)[src] : f2b(((const float*)W)[src]);
  }
  __syncthreads();
#pragma unroll
  for (int i = 0; i < 4; i++)
    WT[(size_t)(n0 + ty + i*8)*K + k0 + tx] = tile[tx][ty + i*8];
}

__global__ __launch_bounds__(256) void cat_kernel(const float* __restrict__ xs,
    const int* __restrict__ xe, const int* __restrict__ xp,
    const float* __restrict__ ee, const float* __restrict__ ep,
    float* __restrict__ CAT){
  int gid = blockIdx.x * 256 + threadIdx.x;   // T*40
  int c = gid % 40; int t = gid / 40; int b = t >> 8;
  float v;
  if (c < 32)      v = xs[(size_t)t*32 + c];
  else if (c < 36) v = ee[xe[b]*4 + (c - 32)];
  else             v = ep[xp[b]*4 + (c - 36)];
  CAT[(size_t)t*40 + c] = v;
}

// SIMT GEMM kept for W_in (K=40, fp32 in/out)
template<typename TA, typename TC>
__global__ __launch_bounds__(256) void gemm_kernel(
    const TA* __restrict__ A, int lda,
    const float* __restrict__ Wm, const float* __restrict__ bias,
    TC* __restrict__ Cc, int ldc, const float* __restrict__ resid,
    int M, int N, int K)
{
  __shared__ float As[16][68];
  __shared__ float Bs[16][68];
  const int bm = blockIdx.y * 64, bn = blockIdx.x * 64;
  const int tid = threadIdx.x, tx = tid & 15, ty = tid >> 4;
  float acc[4][4] = {};
  for (int k0 = 0; k0 < K; k0 += 16){
#pragma unroll
    for (int i = 0; i < 4; i++){
      int idx = tid + i*256;
      int m = idx >> 4, kq = idx & 15;
      As[kq][m] = (k0 + kq < K) ? ldval(A[(size_t)(bm + m)*lda + k0 + kq]) : 0.f;
      int kk = idx >> 6, n = idx & 63;
      Bs[kk][n] = (k0 + kk < K) ? Wm[(size_t)(k0 + kk)*N + bn + n] : 0.f;
    }
    __syncthreads();
#pragma unroll
    for (int kq = 0; kq < 16; kq++){
      float av[4], bv[4];
#pragma unroll
      for (int i = 0; i < 4; i++) av[i] = As[kq][ty*4 + i];
#pragma unroll
      for (int j = 0; j < 4; j++) bv[j] = Bs[kq][tx*4 + j];
#pragma unroll
      for (int i = 0; i < 4; i++)
#pragma unroll
        for (int j = 0; j < 4; j++) acc[i][j] += av[i]*bv[j];
    }
    __syncthreads();
  }
#pragma unroll
  for (int i = 0; i < 4; i++){
    int m = bm + ty*4 + i;
#pragma unroll
    for (int j = 0; j < 4; j++){
      int n = bn + tx*4 + j;
      float v = acc[i][j] + bias[n];
      if (resid) v += resid[(size_t)m*ldc + n];
      stval(&Cc[(size_t)m*ldc + n], v);
    }
  }
}

// MFMA GEMM: 128x128 macro tile, 4 waves 2x2, each 64x64 via 4x4 mfma_16x16x32.
// Double-buffered 2-phase pipeline: ONE barrier per K-step; next-tile global
// loads issue before the MFMA phase and land via ds_write after it (compiler
// inserts the vmcnt wait before the ds_write -> load latency hides under MFMA).
template<typename TC>
__global__ __launch_bounds__(256) void gemm_mfma(
    const u16* __restrict__ A, int lda,
    const u16* __restrict__ WT,
    const float* __restrict__ bias,
    TC* __restrict__ Cc, int ldc, const float* __restrict__ resid,
    int N, int K)
{
  __shared__ alignas(16) u16 As[2][128*40];
  __shared__ alignas(16) u16 Bs[2][128*40];
  const int bm = blockIdx.y * 128, bn = blockIdx.x * 128;
  const int tid = threadIdx.x;
  const int w = tid >> 6, lane = tid & 63, lm = lane & 15, q = lane >> 4;
  const int wm = w >> 1, wn = w & 1;
  // per-thread staging coords (2 chunks/thread): c = tid + i*256, r=c>>2, ch=c&3
  const int r0c = tid >> 2, ch0 = tid & 3;          // chunk 0 row/col
  const int r1c = (tid + 256) >> 2, ch1 = tid & 3;  // chunk 1 row/col
  float4v acc[4][4] = {};

  // prologue: stage k-tile 0 into buffer 0
  {
    *(uint4*)&As[0][r0c*40 + ch0*8] = *(const uint4*)&A[(size_t)(bm + r0c)*lda + ch0*8];
    int n0 = bn + r0c;
    uint4 bv0 = {0u,0u,0u,0u};
    if (n0 < N) bv0 = *(const uint4*)&WT[(size_t)n0*K + ch0*8];
    *(uint4*)&Bs[0][r0c*40 + ch0*8] = bv0;
    *(uint4*)&As[0][r1c*40 + ch1*8] = *(const uint4*)&A[(size_t)(bm + r1c)*lda + ch1*8];
    int n1 = bn + r1c;
    uint4 bv1 = {0u,0u,0u,0u};
    if (n1 < N) bv1 = *(const uint4*)&WT[(size_t)n1*K + ch1*8];
    *(uint4*)&Bs[0][r1c*40 + ch1*8] = bv1;
  }
  __syncthreads();
  int cur = 0;
  for (int k0 = 32; k0 < K; k0 += 32){
    // issue next-tile loads into registers (in flight during MFMA below)
    uint4 av0 = *(const uint4*)&A[(size_t)(bm + r0c)*lda + k0 + ch0*8];
    uint4 av1 = *(const uint4*)&A[(size_t)(bm + r1c)*lda + k0 + ch1*8];
    int n0 = bn + r0c, n1 = bn + r1c;
    uint4 bv0 = {0u,0u,0u,0u}, bv1 = {0u,0u,0u,0u};
    if (n0 < N) bv0 = *(const uint4*)&WT[(size_t)n0*K + k0 + ch0*8];
    if (n1 < N) bv1 = *(const uint4*)&WT[(size_t)n1*K + k0 + ch1*8];
    // compute on current buffer
    short8 a[4], b[4];
#pragma unroll
    for (int i = 0; i < 4; i++)
      a[i] = *(const short8*)&As[cur][(wm*64 + i*16 + lm)*40 + q*8];
#pragma unroll
    for (int j = 0; j < 4; j++)
      b[j] = *(const short8*)&Bs[cur][(wn*64 + j*16 + lm)*40 + q*8];
#pragma unroll
    for (int i = 0; i < 4; i++)
#pragma unroll
      for (int j = 0; j < 4; j++)
        acc[i][j] = __builtin_amdgcn_mfma_f32_16x16x32_bf16(a[i], b[j], acc[i][j], 0, 0, 0);
    // write next buffer (waits vmcnt for the loads above, not the MFMA)
    *(uint4*)&As[cur^1][r0c*40 + ch0*8] = av0;
    *(uint4*)&Bs[cur^1][r0c*40 + ch0*8] = bv0;
    *(uint4*)&As[cur^1][r1c*40 + ch1*8] = av1;
    *(uint4*)&Bs[cur^1][r1c*40 + ch1*8] = bv1;
    __syncthreads();
    cur ^= 1;
  }
  // epilogue: compute last staged tile
  {
    short8 a[4], b[4];
#pragma unroll
    for (int i = 0; i < 4; i++)
      a[i] = *(const short8*)&As[cur][(wm*64 + i*16 + lm)*40 + q*8];
#pragma unroll
    for (int j = 0; j < 4; j++)
      b[j] = *(const short8*)&Bs[cur][(wn*64 + j*16 + lm)*40 + q*8];
#pragma unroll
    for (int i = 0; i < 4; i++)
#pragma unroll
      for (int j = 0; j < 4; j++)
        acc[i][j] = __builtin_amdgcn_mfma_f32_16x16x32_bf16(a[i], b[j], acc[i][j], 0, 0, 0);
  }
#pragma unroll
  for (int i = 0; i < 4; i++){
#pragma unroll
    for (int j = 0; j < 4; j++){
      int col = bn + wn*64 + j*16 + lm;
      if (col < N){
#pragma unroll
        for (int r = 0; r < 4; r++){
          int row = bm + wm*64 + i*16 + q*4 + r;
          float v = acc[i][j][r] + bias[col];
          if (resid) v += resid[(size_t)row*ldc + col];
          stval(&Cc[(size_t)row*ldc + col], v);
        }
      }
    }
  }
}

// LayerNorm: one wave per row, float4 loads, shuffle-only reductions.
__global__ __launch_bounds__(256) void ln_kernel(const float* __restrict__ Xin,
    const float* __restrict__ g, const float* __restrict__ b,
    u16* __restrict__ out, float eps){
  int t = blockIdx.x*4 + (threadIdx.x >> 6);
  int e = threadIdx.x & 63;
  float4 v = *(const float4*)&Xin[(size_t)t*256 + e*4];
  float su = v.x + v.y + v.z + v.w;
#pragma unroll
  for (int o = 32; o > 0; o >>= 1) su += __shfl_xor(su, o, 64);
  float mu = su * (1.f/256.f);
  float d0 = v.x - mu, d1 = v.y - mu, d2 = v.z - mu, d3 = v.w - mu;
  float sq = d0*d0 + d1*d1 + d2*d2 + d3*d3;
#pragma unroll
  for (int o = 32; o > 0; o >>= 1) sq += __shfl_xor(sq, o, 64);
  float rstd = rsqrtf(sq * (1.f/256.f) + eps);
  float4 gv = *(const float4*)&g[e*4];
  float4 bv = *(const float4*)&b[e*4];
  ushort4 o4;
  o4.x = f2b(d0*rstd*gv.x + bv.x);
  o4.y = f2b(d1*rstd*gv.y + bv.y);
  o4.z = f2b(d2*rstd*gv.z + bv.z);
  o4.w = f2b(d3*rstd*gv.w + bv.w);
  *(ushort4*)&out[(size_t)t*256 + e*4] = o4;
}

// depthwise causal conv (K=4) + silu, ushort8 vectorized (8 channels/thread)
__global__ __launch_bounds__(256) void conv_silu_kernel(const u16* __restrict__ Xc, int ldx, int C,
    const float* __restrict__ w, const float* __restrict__ bias, u16* __restrict__ Y){
  int nc = C >> 3;
  long long gid = (long long)blockIdx.x * 256 + threadIdx.x;   // T*nc
  int c8 = (int)(gid % nc) * 8; long long t = gid / nc;
  int s = (int)(t & 255);
  float acc[8];
#pragma unroll
  for (int i = 0; i < 8; i++) acc[i] = bias[c8 + i];
#pragma unroll
  for (int j = 0; j < 4; j++){
    int so = s - 3 + j;
    if (so >= 0){
      ushort8v xv = *(const ushort8v*)&Xc[(size_t)(t - 3 + j)*ldx + c8];
#pragma unroll
      for (int i = 0; i < 8; i++) acc[i] += b2f(xv[i]) * w[j*C + c8 + i];
    }
  }
  ushort8v o8;
#pragma unroll
  for (int i = 0; i < 8; i++) o8[i] = f2b(acc[i] / (1.f + __expf(-acc[i])));
  *(ushort8v*)&Y[(size_t)t*C + c8] = o8;
}

// ipre/fpre: gin=[q|k|v] (T x 1536) @ Wi/Wf (1536 x 4), ushort8 inner loads
__global__ __launch_bounds__(256) void gates_kernel(
    const u16* __restrict__ Q, const u16* __restrict__ Kb, const u16* __restrict__ V,
    const float* __restrict__ Wi, const float* __restrict__ bi,
    const float* __restrict__ Wf, const float* __restrict__ bf,
    float* __restrict__ IP, float* __restrict__ FP){
  int t = blockIdx.x; int tid = threadIdx.x;
  int o = tid & 7, seg = tid >> 3;
  int b = t >> 8, s = t & 255;
  int g = o & 3;
  const float* Wg = (o >= 4) ? Wf : Wi;
  float part = 0.f;
#pragma unroll
  for (int i = 0; i < 6; i++){
    int k8 = seg*48 + i*8;
    const u16* src; int off;
    if (k8 < 512){ src = Q; off = k8; }
    else if (k8 < 1024){ src = Kb; off = k8 - 512; }
    else { src = V; off = k8 - 1024; }
    ushort8v gv = *(const ushort8v*)&src[(size_t)t*512 + off];
#pragma unroll
    for (int j = 0; j < 8; j++) part += b2f(gv[j]) * Wg[(k8 + j)*4 + g];
  }
  __shared__ float red[256];
  red[tid] = part; __syncthreads();
  if (tid < 8){
    float tot = 0.f;
    for (int ss = 0; ss < 32; ss++) tot += red[ss*8 + tid];
    int gg = tid & 3;
    if (tid < 4) IP[(b*4 + gg)*256 + s] = tot + bi[gg];
    else         FP[(b*4 + gg)*256 + s] = tot + bf[gg];
  }
}

// per (b,h): F=cumsum(logsigmoid(fpre)); G=ipre-F; M=cummax(G)
__global__ __launch_bounds__(256) void fscan_kernel(const float* __restrict__ IP,
    const float* __restrict__ FP, float* __restrict__ Fo, float* __restrict__ Go,
    float* __restrict__ Mo){
  int bh = blockIdx.x; int s = threadIdx.x;
  int idx = bh*256 + s;
  __shared__ float buf[256];
  float fp = FP[idx];
  float lfg = fminf(fp, 0.f) - log1pf(expf(-fabsf(fp)));
  float v = lfg;
  buf[s] = v; __syncthreads();
  for (int off = 1; off < 256; off <<= 1){
    float tv = (s >= off) ? buf[s - off] : 0.f;
    __syncthreads();
    v += tv; buf[s] = v;
    __syncthreads();
  }
  float Fv = v;
  float g = IP[idx] - Fv;
  float mv = g;
  buf[s] = mv; __syncthreads();
  for (int off = 1; off < 256; off <<= 1){
    float tv = (s >= off) ? buf[s - off] : -3.0e38f;
    __syncthreads();
    mv = fmaxf(mv, tv); buf[s] = mv;
    __syncthreads();
  }
  Fo[idx] = Fv; Go[idx] = g; Mo[idx] = mv;
}

// Fused MFMA mLSTM attention (unchanged).
__global__ __launch_bounds__(256) void attn_kernel(
    const u16* __restrict__ Q, const u16* __restrict__ Kb, const u16* __restrict__ V,
    const float* __restrict__ G, const float* __restrict__ Mx, const float* __restrict__ F,
    const u16* __restrict__ Ab, const u16* __restrict__ UPb,
    const float* __restrict__ ng, const float* __restrict__ nb,
    const float* __restrict__ skip, u16* __restrict__ Yb)
{
  int bh = blockIdx.y, b = bh >> 2, h = bh & 3;
  int tt = blockIdx.x, t0 = tt * 64;
  int tid = threadIdx.x;
  int w = tid >> 6, lane = tid & 63, lm = lane & 15, q = lane >> 4;
  int gbase = bh * 256;

  __shared__ alignas(16) u16 Qs[64*136];
  __shared__ alignas(16) u16 Ks[64*136];
  __shared__ alignas(16) u16 Vt[128*72];
  __shared__ alignas(16) u16 Ps[64*72];
  __shared__ float rs[64];

#pragma unroll
  for (int c = tid; c < 1024; c += 256){
    int r = c >> 4, ch = c & 15;
    *(uint4*)&Qs[r*136 + ch*8] =
      *(const uint4*)&Q[((size_t)(b*256 + t0 + r))*512 + h*128 + ch*8];
  }
  if (tid < 64) rs[tid] = 0.f;

  float mrow[4];
#pragma unroll
  for (int r = 0; r < 4; r++) mrow[r] = Mx[gbase + t0 + w*16 + q*4 + r];

  float4v acc2[8] = {};
  const float scale = 0.08838834764831845f;

  for (int ss = 0; ss <= tt; ss++){
    int s0 = ss * 64;
    __syncthreads();
#pragma unroll
    for (int c = tid; c < 1024; c += 256){
      int r = c >> 4, ch = c & 15;
      *(uint4*)&Ks[r*136 + ch*8] =
        *(const uint4*)&Kb[((size_t)(b*256 + s0 + r))*512 + h*128 + ch*8];
    }
#pragma unroll
    for (int c = tid; c < 1024; c += 256){
      int sl = c & 63, db = c >> 6;
      ushort8v v = *(const ushort8v*)&V[((size_t)(b*256 + s0 + sl))*512 + h*128 + db*8];
#pragma unroll
      for (int j = 0; j < 8; j++) Vt[(db*8 + j)*72 + sl] = v[j];
    }
    __syncthreads();
    float4v sacc[4] = {};
#pragma unroll
    for (int k0 = 0; k0 < 128; k0 += 32){
      short8 a = *(const short8*)&Qs[(w*16 + lm)*136 + k0 + q*8];
#pragma unroll
      for (int j = 0; j < 4; j++){
        short8 bb = *(const short8*)&Ks[(j*16 + lm)*136 + k0 + q*8];
        sacc[j] = __builtin_amdgcn_mfma_f32_16x16x32_bf16(a, bb, sacc[j], 0, 0, 0);
      }
    }
    float rp[4] = {0.f, 0.f, 0.f, 0.f};
#pragma unroll
    for (int j = 0; j < 4; j++){
      int scol = s0 + j*16 + lm;
      float gq = G[gbase + scol];
#pragma unroll
      for (int r = 0; r < 4; r++){
        int trow = t0 + w*16 + q*4 + r;
        float cval = (scol <= trow) ? sacc[j][r]*scale*__expf(gq - mrow[r]) : 0.f;
        Ps[(w*16 + q*4 + r)*72 + j*16 + lm] = f2b(cval);
        rp[r] += cval;
      }
    }
#pragma unroll
    for (int r = 0; r < 4; r++){
#pragma unroll
      for (int m = 1; m < 16; m <<= 1) rp[r] += __shfl_xor(rp[r], m, 16);
      if (lm == 0) rs[w*16 + q*4 + r] += rp[r];
    }
#pragma unroll
    for (int k0 = 0; k0 < 64; k0 += 32){
      short8 a = *(const short8*)&Ps[(w*16 + lm)*72 + k0 + q*8];
#pragma unroll
      for (int jd = 0; jd < 8; jd++){
        short8 bb = *(const short8*)&Vt[(jd*16 + lm)*72 + k0 + q*8];
        acc2[jd] = __builtin_amdgcn_mfma_f32_16x16x32_bf16(a, bb, acc2[jd], 0, 0, 0);
      }
    }
  }
  __syncthreads();
#pragma unroll
  for (int r = 0; r < 4; r++){
    int rl = w*16 + q*4 + r;
    int t = t0 + rl;
    float Fv = F[gbase + t];
    float nrm = fmaxf(fabsf(rs[rl]), __expf(-(Fv + mrow[r])));
    float inv = 1.f / nrm;
    float vv[8];
    float su = 0.f;
#pragma unroll
    for (int jd = 0; jd < 8; jd++){ vv[jd] = acc2[jd][r]*inv; su += vv[jd]; }
#pragma unroll
    for (int m = 1; m < 16; m <<= 1) su += __shfl_xor(su, m, 16);
    float mu = su * (1.f/128.f);
    float sq = 0.f;
#pragma unroll
    for (int jd = 0; jd < 8; jd++){ vv[jd] -= mu; sq += vv[jd]*vv[jd]; }
#pragma unroll
    for (int m = 1; m < 16; m <<= 1) sq += __shfl_xor(sq, m, 16);
    float rstd = rsqrtf(sq * (1.f/128.f) + 1e-6f);
#pragma unroll
    for (int jd = 0; jd < 8; jd++){
      int c = h*128 + jd*16 + lm;
      float hv = vv[jd]*rstd*ng[c] + nb[c];
      float av = b2f(Ab[(size_t)t*512 + c]);
      float zg = b2f(UPb[(size_t)t*1024 + 512 + c]);
      float sz = zg / (1.f + __expf(-zg));
      Yb[(size_t)t*512 + c] = f2b((hv + skip[c]*av)*sz);
    }
  }
}

// sLSTM recurrence: 5 waves per (b,h), per-step streaming, __syncthreads.
// (R10's raw-barrier + sched fences regressed 194->221us: the fences blocked
// compiler ILP across phase boundaries. Data layout from R10 kept.)
// Gate inputs: G1 = [IT|FT], G2 = [ZT|OT], stride 512; wave w streams its own
// column block 2 steps ahead.
//  - waves 0..3: matvec over 16 d's each -> float4 partial -> LDS; barrier;
//    replicated 4-way reduce + scalar tail (bitwise identical) keeps
//    (h,c,n,m) in all 4 waves; wave 1 publishes h to 2-slot hbuf ring.
//  - wave 4: one step behind; DPP headnorm + Xr read-add-write.
//  - 257 barriers on both divergent paths.
__global__ __launch_bounds__(320) void scan_kernel(
    const float* __restrict__ G1, const float* __restrict__ G2,
    const float* __restrict__ Ri, const float* __restrict__ Rf,
    const float* __restrict__ Rz, const float* __restrict__ Ro,
    const float* __restrict__ sng, const float* __restrict__ snb,
    float* __restrict__ Xr){
  int bh = blockIdx.x; int b = bh >> 2, h = bh & 3;
  int e = threadIdx.x & 63;
  int w = threadIdx.x >> 6;                 // 0..4, wave-uniform
  __shared__ float4 part[2][4][64];         // [s&1][wave][e] = 4 gate partials
  __shared__ float hbuf[2][64];             // [s&1][e] = h(s)
  size_t xrow = ((size_t)b*256)*256 + h*64 + e;   // Xr stride 256

  if (w < 4){
    // R fragments: rX[k] = R_X[h][w*16+k][e]
    float r0[16], r1[16], r2[16], r3[16];
    const float* Rp0 = Ri + h*4096 + w*1024;
    const float* Rp1 = Rf + h*4096 + w*1024;
    const float* Rp2 = Rz + h*4096 + w*1024;
    const float* Rp3 = Ro + h*4096 + w*1024;
#pragma unroll
    for (int d = 0; d < 16; d++){
      r0[d] = Rp0[d*64 + e];
      r1[d] = Rp1[d*64 + e];
      r2[d] = Rp2[d*64 + e];
      r3[d] = Rp3[d*64 + e];
    }
    // this wave's gate stream: stride 512, col block (w&1)*256
    const float* Gp = (w < 2) ? G1 : G2;
    size_t grow = ((size_t)b*256)*512 + ((w & 1) ? 256 : 0) + h*64 + e;
    float hS = 0.f, cS = 0.f, nS = 0.f, mS = 0.f;
    float gv = Gp[grow];                       // s = 0
    float gn = Gp[grow + 512];                 // s = 1
    for (int s = 0; s < 256; s++){
      float gn2 = 0.f;
      if (s < 254) gn2 = Gp[grow + (size_t)(s + 2)*512];
      // phase A: partial matvec over this wave's 16 d's (8 chains)
      float ai0 = 0.f, ai1 = 0.f, af0 = 0.f, af1 = 0.f;
      float az0 = 0.f, az1 = 0.f, ao0 = 0.f, ao1 = 0.f;
#pragma unroll
      for (int k = 0; k < 16; k += 2){
        float h0 = __builtin_bit_cast(float,
            __builtin_amdgcn_readlane(__builtin_bit_cast(int, hS), w*16 + k));
        float h1 = __builtin_bit_cast(float,
            __builtin_amdgcn_readlane(__builtin_bit_cast(int, hS), w*16 + k + 1));
        ai0 += h0*r0[k]; ai1 += h1*r0[k+1];
        af0 += h0*r1[k]; af1 += h1*r1[k+1];
        az0 += h0*r2[k]; az1 += h1*r2[k+1];
        ao0 += h0*r3[k]; ao1 += h1*r3[k+1];
      }
      float4 p;
      p.x = ai0 + ai1; p.y = af0 + af1; p.z = az0 + az1; p.w = ao0 + ao1;
      if      (w == 0) p.x += gv;
      else if (w == 1) p.y += gv;
      else if (w == 2) p.z += gv;
      else             p.w += gv;
      part[s & 1][w][e] = p;
      __syncthreads();
      // phase B: replicated reduce + scalar tail (bitwise identical, 4 waves)
      float4 q0 = part[s & 1][0][e];
      float4 q1 = part[s & 1][1][e];
      float4 q2 = part[s & 1][2][e];
      float4 q3 = part[s & 1][3][e];
      float ip = (q0.x + q1.x) + (q2.x + q3.x);
      float fp = (q0.y + q1.y) + (q2.y + q3.y);
      float zr = (q0.z + q1.z) + (q2.z + q3.z);
      float og = (q0.w + q1.w) + (q2.w + q3.w);
      float zp = 1.f - 2.f*__builtin_amdgcn_rcpf(__expf(2.f*zr) + 1.f);
      float op = __builtin_amdgcn_rcpf(1.f + __expf(-og));
      float mn = fmaxf(fp + mS, ip);
      float ig = __expf(ip - mn);
      float fg = __expf(fp + mS - mn);
      cS = fg*cS + ig*zp;
      nS = fg*nS + ig;
      mS = mn;
      hS = op * cS * __builtin_amdgcn_rcpf(nS);
      if (w == 1) hbuf[s & 1][e] = hS;
      gv = gn; gn = gn2;
    }
    __syncthreads();  // pairs with wave 4's epilogue barrier
  } else {
    // output wave: one step behind; DPP headnorm; per-step Xr stream
    float gw = sng[h*64 + e], bw = snb[h*64 + e];
    float xp = 0.f, xc = 0.f;
    for (int s = 0; s < 256; s++){
      xc = Xr[xrow + (size_t)s*256];
      __syncthreads();
      if (s > 0){
        float hv = hbuf[(s - 1) & 1][e];
        float su, sq;
        dpp_sum2(hv, hv*hv, su, sq);
        float mu = su * (1.f/64.f);
        float var = fmaxf(sq * (1.f/64.f) - mu*mu, 0.f);
        float nv = (hv - mu) * rsqrtf(var + 1e-6f) * gw + bw;
        Xr[xrow + (size_t)(s - 1)*256] = xp + nv;
      }
      xp = xc;
    }
    __syncthreads();
    // epilogue: row 255 (h(255) in slot 255&1 == 1)
    float hv = hbuf[1][e];
    float su, sq;
    dpp_sum2(hv, hv*hv, su, sq);
    float mu = su * (1.f/64.f);
    float var = fmaxf(sq * (1.f/64.f) - mu*mu, 0.f);
    float nv = (hv - mu) * rsqrtf(var + 1e-6f) * gw + bw;
    Xr[xrow + (size_t)255*256] = xp + nv;
  }
}

// FFN activation: P = gelu_tanh(g) * u, ushort8 vectorized
__global__ __launch_bounds__(256) void ffn_act_kernel(const u16* __restrict__ GU,
                                                      u16* __restrict__ P){
  long long gid = (long long)blockIdx.x * 256 + threadIdx.x;   // T*44
  int j8 = (int)(gid % 44) * 8; long long t = gid / 44;
  ushort8v gv = *(const ushort8v*)&GU[(size_t)t*704 + j8];
  ushort8v uv = *(const ushort8v*)&GU[(size_t)t*704 + 352 + j8];
  ushort8v o8;
#pragma unroll
  for (int i = 0; i < 8; i++){
    float g = b2f(gv[i]);
    float u = b2f(uv[i]);
    float inner = 0.7978845608028654f * (g + 0.044715f*g*g*g);
    float gel = 0.5f * g * (1.f + tanhf(inner));
    o8[i] = f2b(gel * u);
  }
  *(ushort8v*)&P[(size_t)t*352 + j8] = o8;
}

// output head: relu(last@W1+b1)@W2+b2, write in detected dtype
__global__ __launch_bounds__(64) void head_kernel(const float* __restrict__ X,
    const float* __restrict__ W1, const float* __restrict__ b1,
    const float* __restrict__ W2, const float* __restrict__ b2,
    void* out, const int* __restrict__ flag){
  int b = blockIdx.x, j = threadIdx.x;
  __shared__ float L[256];
  __shared__ float H1[64];
  for (int i = j; i < 256; i += 64) L[i] = X[((size_t)(b*256 + 255))*256 + i];
  __syncthreads();
  float acc = b1[j];
  for (int d = 0; d < 256; d++) acc += L[d] * W1[d*64 + j];
  H1[j] = fmaxf(acc, 0.f);
  __syncthreads();
  if (j < 3){
    float o = b2[j];
    for (int k2 = 0; k2 < 64; k2++) o += H1[k2] * W2[k2*3 + j];
    if (*flag) ((u16*)out)[b*3 + j] = f2b(o);
    else       ((float*)out)[b*3 + j] = o;
  }
}

// ----------------------------- launch --------------------------------------
extern "C" void kernel_launch(void* const* d_in, const int* in_sizes, int n_in,
                              void* d_out, int out_size, void* d_ws, size_t ws_size,
                              hipStream_t stream)
{
  if (n_in != IN_N) return;
  for (int i = 0; i < IN_N; i++) if ((long long)in_sizes[i] != IN_SIZES[i]) return;
  if (ws_size < (size_t)WS_END * 4) return;
  if (out_size != 384) return;

  float* ws = (float*)d_ws;
  float* cv = ws;
  auto cvp = [&](int i){ return cv + CVOFF.off[i]; };

  int*   flag = (int*)(ws + OFF_FLAG);
  float* IP   = ws + OFF_IP;
  float* FP   = ws + OFF_FP;
  float* Fb   = ws + OFF_F;
  float* Gb   = ws + OFF_G;
  float* Mb   = ws + OFF_M;
  float* X    = ws + OFF_X;
  u16*   XNb  = (u16*)(ws + OFF_XN);
  u16*   UPb  = (u16*)(ws + OFF_UP);
  u16*   Ab   = (u16*)(ws + OFF_A);
  u16*   Qb   = (u16*)(ws + OFF_Q);
  u16*   Kbb  = (u16*)(ws + OFF_K);
  u16*   Vb   = (u16*)(ws + OFF_V);
  u16*   WTb  = (u16*)(ws + OFF_WT);
  // overlays (lifetimes disjoint):
  float* CAT = ws + OFF_V;
  u16*   Yb  = Qb;
  u16*   ACb = Ab;
  float* G1f = ws + OFF_K;    // [T x 512] fp32: IT|FT (spans OFF_K + OFF_V)
  float* G2f = ws + OFF_UP;   // [T x 512] fp32: ZT|OT (spans OFF_UP)
  u16*   GUb = UPb;
  u16*   Pb  = Ab;

  auto wt = [&](int widx){ return WTb + WTO[widx]; };

  InPtrs ptrs;
  for (int i = 0; i < IN_N; i++) ptrs.p[i] = d_in[i];

  const int M = 32768;
  detect_kernel<<<1, 64, 0, stream>>>(d_in[7], flag);
  int cvblocks = (int)((CV_TOTAL + 255) / 256);
  convert_kernel<<<cvblocks, 256, 0, stream>>>(ptrs, cv, flag);
  wtrans_kernel<<<dim3(32, 16, 11), 256, 0, stream>>>(ptrs, WTb, flag);
  cat_kernel<<<5120, 256, 0, stream>>>(cvp(0), (const int*)d_in[1], (const int*)d_in[2],
                                       cvp(3), cvp(4), CAT);
  gemm_kernel<float, float><<<dim3(4, 512), 256, 0, stream>>>(CAT, 40, cvp(5), cvp(6),
      X, 256, nullptr, M, 256, 40);
  // ---- mLSTM block ----
  ln_kernel<<<8192, 256, 0, stream>>>(X, cvp(7), cvp(8), XNb, 1e-5f);
  gemm_mfma<u16><<<dim3(8, 256), 256, 0, stream>>>(XNb, 256, wt(0), cvp(10),
      UPb, 1024, nullptr, 1024, 256);
  conv_silu_kernel<<<8192, 256, 0, stream>>>(UPb, 1024, 512, cvp(11), cvp(12), Ab);
  gemm_mfma<u16><<<dim3(4, 256), 256, 0, stream>>>(Ab, 512, wt(1), cvp(14),
      Qb, 512, nullptr, 512, 512);
  gemm_mfma<u16><<<dim3(4, 256), 256, 0, stream>>>(Ab, 512, wt(2), cvp(16),
      Kbb, 512, nullptr, 512, 512);
  gemm_mfma<u16><<<dim3(4, 256), 256, 0, stream>>>(UPb, 1024, wt(3), cvp(18),
      Vb, 512, nullptr, 512, 512);
  gates_kernel<<<M, 256, 0, stream>>>(Qb, Kbb, Vb, cvp(19), cvp(20), cvp(21), cvp(22), IP, FP);
  fscan_kernel<<<512, 256, 0, stream>>>(IP, FP, Fb, Gb, Mb);
  attn_kernel<<<dim3(4, 512), 256, 0, stream>>>(Qb, Kbb, Vb, Gb, Mb, Fb,
      Ab, UPb, cvp(24), cvp(25), cvp(23), Yb);
  gemm_mfma<float><<<dim3(2, 256), 256, 0, stream>>>(Yb, 512, wt(4), cvp(27),
      X, 256, X, 256, 512);
  // ---- sLSTM block ----
  ln_kernel<<<8192, 256, 0, stream>>>(X, cvp(28), cvp(29), XNb, 1e-5f);
  conv_silu_kernel<<<4096, 256, 0, stream>>>(XNb, 256, 256, cvp(30), cvp(31), ACb);
  // merged gate GEMMs: [AC]@[s_Wi|s_Wf] -> G1 (IT|FT), [XN]@[s_Wz|s_Wo] -> G2
  gemm_mfma<float><<<dim3(4, 256), 256, 0, stream>>>(ACb, 256, wt(5), cvp(33),
      G1f, 512, nullptr, 512, 256);
  gemm_mfma<float><<<dim3(4, 256), 256, 0, stream>>>(XNb, 256, wt(7), cvp(37),
      G2f, 512, nullptr, 512, 256);
  scan_kernel<<<512, 320, 0, stream>>>(G1f, G2f, cvp(40), cvp(41), cvp(42), cvp(43),
      cvp(44), cvp(45), X);
  // ---- FFN ----
  ln_kernel<<<8192, 256, 0, stream>>>(X, cvp(46), cvp(47), XNb, 1e-5f);
  gemm_mfma<u16><<<dim3(6, 256), 256, 0, stream>>>(XNb, 256, wt(9), cvp(49),
      GUb, 704, nullptr, 704, 256);
  ffn_act_kernel<<<5632, 256, 0, stream>>>(GUb, Pb);
  gemm_mfma<float><<<dim3(2, 256), 256, 0, stream>>>(Pb, 352, wt(10), cvp(51),
      X, 256, X, 256, 352);
  // ---- head ----
  head_kernel<<<128, 64, 0, stream>>>(X, cvp(52), cvp(53), cvp(54), cvp(55), d_out, flag);
}